// Round 4
// baseline (1534.540 us; speedup 1.0000x reference)
//
#include <hip/hip_runtime.h>
#include <math.h>

#define BB 16
#define NN 1024
#define DD 256

typedef unsigned short u16;
typedef unsigned int uint32;
typedef __attribute__((ext_vector_type(8))) short s8v;   // 8 bf16 (4 VGPRs)
typedef __attribute__((ext_vector_type(4))) float f4v;   // 4 fp32 acc

__device__ __forceinline__ u16 f2b(float f) {            // RNE fp32->bf16
  uint32 u = __float_as_uint(f);
  return (u16)((u + 0x7fffu + ((u >> 16) & 1u)) >> 16);
}
__device__ __forceinline__ float b2f(u16 u) {
  return __uint_as_float(((uint32)u) << 16);
}

__device__ __forceinline__ float waveRedSum(float v) {
  #pragma unroll
  for (int o = 32; o; o >>= 1) v += __shfl_xor(v, o, 64);
  return v;
}
__device__ __forceinline__ float waveRedMax(float v) {
  #pragma unroll
  for (int o = 32; o; o >>= 1) v = fmaxf(v, __shfl_xor(v, o, 64));
  return v;
}

// ---------------------------------------------------------------- pts [B,N,3]
__global__ void k_pts(const float* __restrict__ x, float* __restrict__ pts) {
  int i = blockIdx.x * 256 + threadIdx.x;
  if (i >= BB * NN) return;
  int b = i >> 10, n = i & 1023;
  const float* xb = x + (size_t)b * 3 * NN;
  pts[i * 3 + 0] = xb[n];
  pts[i * 3 + 1] = xb[NN + n];
  pts[i * 3 + 2] = xb[2 * NN + n];
}

// ---------------------------------------------------------------- eA fp32 [bn][256] float2
__global__ void k_phase(const float* __restrict__ pts, const float* __restrict__ A,
                        float2* __restrict__ eA) {
  int i = blockIdx.x * 256 + threadIdx.x;            // (b*N+n)*256 + d
  int d = i & 255; int bn = i >> 8;
  float p0 = pts[bn * 3], p1 = pts[bn * 3 + 1], p2 = pts[bn * 3 + 2];
  float ta = p0 * A[d] + p1 * A[256 + d] + p2 * A[512 + d];
  float s, c;
  sincosf(ta, &s, &c); eA[i] = make_float2(c, s);
}

// ---------------------------------------------------------------- eA -> eAT bf16 [b][512][1024]
__global__ void k_eat(const float2* __restrict__ eA, u16* __restrict__ eAT) {
  int bid = blockIdx.x;
  int dt = bid & 7, nt = (bid >> 3) & 15, b = bid >> 7;
  int d0 = dt * 32, n0 = nt * 64;
  __shared__ u16 cosT[32][72], sinT[32][72];
  int t = threadIdx.x;
  {
    int n = t >> 2, dg = (t & 3) * 8;
    const float2* p = eA + ((size_t)(b * 1024 + n0 + n)) * 256 + d0 + dg;
    #pragma unroll
    for (int j = 0; j < 8; j++) {
      float2 v = p[j];
      cosT[dg + j][n] = f2b(v.x);
      sinT[dg + j][n] = f2b(v.y);
    }
  }
  __syncthreads();
  {
    int rr = t >> 2, ng = (t & 3) * 16;
    int d = rr >> 1, cmp = rr & 1;
    const u16* src = (cmp ? &sinT[d][ng] : &cosT[d][ng]);
    uint4 v0 = *(const uint4*)src;
    uint4 v1 = *(const uint4*)(src + 8);
    u16* dst = eAT + ((size_t)(b * 512 + 2 * d0 + rr)) * 1024 + n0 + ng;
    *(uint4*)dst = v0;
    *(uint4*)(dst + 8) = v1;
  }
}

// ---------------------------------------------------------------- J bf16 [b][n][1024]
__global__ void k_jbuild(const float* __restrict__ pts, u16* __restrict__ J) {
  int bid = blockIdx.x;                 // b*1024 + n
  int b = bid >> 10, n = bid & 1023;
  int t = threadIdx.x;
  const float* pb = pts + (size_t)b * 3072;
  float pnx = pb[n * 3], pny = pb[n * 3 + 1], pnz = pb[n * 3 + 2];
  int m = t * 4;
  const float* pm = pb + (size_t)m * 3;
  float4 a = *(const float4*)pm;
  float4 bq = *(const float4*)(pm + 4);
  float4 c = *(const float4*)(pm + 8);
  float dx, dy, dz, d2;
  dx = a.x - pnx;  dy = a.y - pny;  dz = a.z - pnz;  d2 = dx*dx + dy*dy + dz*dz;
  float j0 = __expf(-18.0f * d2);
  dx = a.w - pnx;  dy = bq.x - pny; dz = bq.y - pnz; d2 = dx*dx + dy*dy + dz*dz;
  float j1 = __expf(-18.0f * d2);
  dx = bq.z - pnx; dy = bq.w - pny; dz = c.x - pnz;  d2 = dx*dx + dy*dy + dz*dz;
  float j2 = __expf(-18.0f * d2);
  dx = c.y - pnx;  dy = c.z - pny;  dz = c.w - pnz;  d2 = dx*dx + dy*dy + dz*dz;
  float j3 = __expf(-18.0f * d2);
  uint32 lo = (uint32)f2b(j0) | ((uint32)f2b(j1) << 16);
  uint32 hi = (uint32)f2b(j2) | ((uint32)f2b(j3) << 16);
  *(uint2*)(J + (size_t)bid * 1024 + m) = make_uint2(lo, hi);
}

// ------------------------------------------ G = norm(M*conj(eA))*16 + exp(i pts@P) -> interleaved bf16 [bn][512]
__global__ void k_norm(const float2* __restrict__ M, const float2* __restrict__ eA,
                       const float* __restrict__ pts, const float* __restrict__ P,
                       u16* __restrict__ Gb) {
  int bn = blockIdx.x; int c = threadIdx.x;
  size_t idx = (size_t)bn * DD + c;
  float2 m = M[idx], e = eA[idx];
  float gr = m.x * e.x + m.y * e.y;
  float gi = m.y * e.x - m.x * e.y;
  float s = gr * gr + gi * gi;
  s = waveRedSum(s);
  __shared__ float red[4];
  if ((c & 63) == 0) red[c >> 6] = s;
  __syncthreads();
  float tot = red[0] + red[1] + red[2] + red[3];
  float scale = 16.0f / sqrtf(tot);
  float p0 = pts[bn * 3], p1 = pts[bn * 3 + 1], p2 = pts[bn * 3 + 2];
  float tp = p0 * P[c] + p1 * P[256 + c] + p2 * P[512 + c];
  float sp, cp; sincosf(tp, &sp, &cp);
  uint32 pk = (uint32)f2b(gr * scale + cp) | ((uint32)f2b(gi * scale + sp) << 16);
  *(uint32*)(Gb + idx * 2) = pk;
}

// ---------------------------------------------------------------- weight casts / complex-weight prep
__global__ void k_cast(const float* __restrict__ s, u16* __restrict__ d, int n) {
  int i = blockIdx.x * 256 + threadIdx.x;
  if (i < n) d[i] = f2b(s[i]);
}
__global__ void k_wprep(const float* __restrict__ wr, const float* __restrict__ wi,
                        u16* __restrict__ dst) {
  int i = blockIdx.x * 256 + threadIdx.x;   // 512*512
  int op = i >> 9, c2 = i & 511, c = c2 >> 1, pl = c2 & 1;
  float v;
  if (op < 256) v = pl ? -wi[op * 256 + c] : wr[op * 256 + c];
  else          v = pl ?  wr[(op - 256) * 256 + c] : wi[(op - 256) * 256 + c];
  dst[i] = f2b(v);
}
__global__ void k_cbias(const float* __restrict__ br, const float* __restrict__ bi,
                        float* __restrict__ cb) {
  int t = threadIdx.x;
  cb[t] = (t < 256) ? br[t] : bi[t - 256];
}

// ---------------------------------------------------------------- Gr=|G|^2 -> bigT[:,1024+c] bf16
__global__ void k_g2(const u16* __restrict__ G2b, u16* __restrict__ bigT) {
  int i = blockIdx.x * 256 + threadIdx.x;   // 16384*256
  int row = i >> 8, c = i & 255;
  float re = b2f(G2b[(size_t)row * 512 + 2 * c]);
  float im = b2f(G2b[(size_t)row * 512 + 2 * c + 1]);
  bigT[(size_t)row * 1280 + 1024 + c] = f2b(re * re + im * im);
}

// ---------------------------------------------------------------- generic bf16 MFMA GEMM
// D[M][N] = A[M][K] * Bt[N][K]^T  (both bf16, k-contiguous), fp32 accum.
// LDS strides 36 (tiles) / BM+8 (transpose) for conflict-free b128 access.
template<int BM>
__launch_bounds__(256)
__global__ void k_mm(const u16* __restrict__ Ab, long a_bs, int lda,
                     const u16* __restrict__ Btb, long b_bs, int ldb,
                     int K, int tiles_m, int tiles_n,
                     const float* __restrict__ bias,
                     const float* __restrict__ bng, const float* __restrict__ bnb,
                     const float* __restrict__ cbias,
                     int act,
                     const float* __restrict__ res, long res_bs, int res_sub,
                     float* __restrict__ outF, long outF_bs, int ldF,
                     u16* __restrict__ outB, long outB_bs, int ldBo, int ileave,
                     u16* __restrict__ outT, long outT_bs, int ldT,
                     float* __restrict__ outPool) {
  constexpr int BN = 128;
  constexpr int WM = (BM == 128) ? 64 : 32;
  constexpr int MI = WM / 16;
  constexpr int TLD = BM + 8;
  __shared__ u16 smem[BN * TLD];           // As(BM*36)+Bs(128*36) | transpose [BN][TLD]
  u16* As = smem;
  u16* Bs = smem + BM * 36;
  int t = threadIdx.x;
  int l = t & 63, w = t >> 6;
  int p = l & 15, q = l >> 4;
  int bid = blockIdx.x;
  int tn = bid % tiles_n;
  int tm = (bid / tiles_n) % tiles_m;
  int b  = bid / (tiles_n * tiles_m);
  int m0 = tm * BM, n0 = tn * BN;
  int wm = w >> 1, wn = w & 1;
  const u16* Ap = Ab + (size_t)b * a_bs;
  const u16* Bp = Btb + (size_t)b * b_bs;

  f4v acc[MI][4];
  #pragma unroll
  for (int i = 0; i < MI; i++)
    #pragma unroll
    for (int j = 0; j < 4; j++) acc[i][j] = (f4v){0.f, 0.f, 0.f, 0.f};

  int arow = t >> 2, kg = (t & 3) * 8;
  for (int k0 = 0; k0 < K; k0 += 32) {
    __syncthreads();
    #pragma unroll
    for (int it = 0; it < BM / 64; it++) {
      int r = it * 64 + arow;
      float4 v = *(const float4*)(Ap + (size_t)(m0 + r) * lda + k0 + kg);
      *(float4*)&As[r * 36 + kg] = v;
    }
    #pragma unroll
    for (int it = 0; it < 2; it++) {
      int r = it * 64 + arow;
      float4 v = *(const float4*)(Bp + (size_t)(n0 + r) * ldb + k0 + kg);
      *(float4*)&Bs[r * 36 + kg] = v;
    }
    __syncthreads();
    s8v af[MI], bf[4];
    #pragma unroll
    for (int i = 0; i < MI; i++)
      af[i] = *(const s8v*)&As[(wm * WM + i * 16 + p) * 36 + q * 8];
    #pragma unroll
    for (int j = 0; j < 4; j++)
      bf[j] = *(const s8v*)&Bs[(wn * 64 + j * 16 + p) * 36 + q * 8];
    #pragma unroll
    for (int i = 0; i < MI; i++)
      #pragma unroll
      for (int j = 0; j < 4; j++)
        acc[i][j] = __builtin_amdgcn_mfma_f32_16x16x32_bf16(af[i], bf[j], acc[i][j], 0, 0, 0);
  }

  __syncthreads();   // LDS now free for reuse

  float cbv[4];
  #pragma unroll
  for (int j = 0; j < 4; j++) {
    int no = n0 + wn * 64 + j * 16 + p;
    cbv[j] = cbias ? cbias[no] : 0.0f;
  }
  float pmax[MI][4];
  #pragma unroll
  for (int i = 0; i < MI; i++)
    #pragma unroll
    for (int r = 0; r < 4; r++) pmax[i][r] = -3.0e38f;
  const float BNS = 0.99999500003749966f;  // 1/sqrt(1+1e-5)
  #pragma unroll
  for (int i = 0; i < MI; i++) {
    #pragma unroll
    for (int r = 0; r < 4; r++) {
      int mo = m0 + wm * WM + i * 16 + q * 4 + r;
      float mult = 1.f, add = 0.f;
      if (bias) add = bias[mo];
      if (bng) { float s = bng[mo] * BNS; add = add * s + bnb[mo]; mult = s; }
      #pragma unroll
      for (int j = 0; j < 4; j++) {
        int no = n0 + wn * 64 + j * 16 + p;
        float v = acc[i][j][r];
        v = v * mult + add;
        if (cbias) v += cbv[j];
        if (act == 1) v = fmaxf(v, 0.f);
        else if (act == 2) v = v > 0.f ? v : 0.2f * v;
        if (res) {
          float rv = res[(size_t)b * res_bs + (size_t)mo * NN + no];
          v = res_sub ? rv - v : rv + v;
        }
        if (outPool) pmax[i][r] = fmaxf(pmax[i][r], v);
        if (outF) outF[(size_t)b * outF_bs + (size_t)mo * ldF + no] = v;
        if (outB) {
          int noo = ileave ? (((no & 255) << 1) | (no >> 8)) : no;
          outB[(size_t)b * outB_bs + (size_t)mo * ldBo + noo] = f2b(v);
        }
        if (outT) smem[(wn * 64 + j * 16 + p) * TLD + (mo - m0)] = f2b(v);
      }
    }
  }
  if (outT) {
    __syncthreads();
    constexpr int CPR = BM / 8;            // threads per row (8 bf16 each)
    constexpr int RPP = 256 / CPR;
    int row0 = t / CPR, cg = (t % CPR) * 8;
    for (int rr = row0; rr < BN; rr += RPP) {
      float4 v = *(const float4*)&smem[rr * TLD + cg];
      *(float4*)(outT + (size_t)b * outT_bs + (size_t)(n0 + rr) * ldT + m0 + cg) = v;
    }
  }
  if (outPool) {
    float* pf = (float*)smem;              // [BM][2]
    #pragma unroll
    for (int i = 0; i < MI; i++)
      #pragma unroll
      for (int r = 0; r < 4; r++) {
        float m = pmax[i][r];
        #pragma unroll
        for (int o = 1; o < 16; o <<= 1) m = fmaxf(m, __shfl_xor(m, o, 64));
        if (p == 0) pf[(wm * WM + i * 16 + q * 4 + r) * 2 + wn] = m;
      }
    __syncthreads();
    if (t < BM) {
      float mv = fmaxf(pf[t * 2], pf[t * 2 + 1]);
      outPool[((size_t)b * (tiles_m * BM) + m0 + t) * tiles_n + tn] = mv;
    }
  }
}

// ---------------------------------------------------------------- partial softmax stats of E (E never stored)
// E tile [128 rt-rows][128 ct-cols] via MFMA from xkT; emit per-row (tilemax, sum exp(e-tilemax))
__launch_bounds__(256)
__global__ void k_estats(const u16* __restrict__ xkT_, float* __restrict__ part) {
  __shared__ u16 As[128 * 72];
  __shared__ u16 Bs[128 * 72];
  __shared__ float lred[128][2];
  __shared__ float gm[128];
  __shared__ float lsum[128][2];
  int t = threadIdx.x;
  int l = t & 63, w = t >> 6;
  int p = l & 15, q = l >> 4;
  int wm = w >> 1, wn = w & 1;
  int bid = blockIdx.x;
  int ct = bid & 7, rt = (bid >> 3) & 7, b = bid >> 6;
  const u16* xkp = xkT_ + (size_t)b * 65536;
  {
    int kg = (t & 7) * 8;
    int r0 = t >> 3;
    #pragma unroll
    for (int it = 0; it < 4; it++) {
      int r = it * 32 + r0;
      *(float4*)&As[r * 72 + kg] = *(const float4*)(xkp + (size_t)(rt * 128 + r) * 64 + kg);
      *(float4*)&Bs[r * 72 + kg] = *(const float4*)(xkp + (size_t)(ct * 128 + r) * 64 + kg);
    }
  }
  __syncthreads();
  f4v acc[4][4];
  #pragma unroll
  for (int i = 0; i < 4; i++)
    #pragma unroll
    for (int j = 0; j < 4; j++) acc[i][j] = (f4v){0.f, 0.f, 0.f, 0.f};
  #pragma unroll
  for (int ks = 0; ks < 2; ks++) {
    int ko = ks * 32 + q * 8;
    s8v af[4], bf[4];
    #pragma unroll
    for (int i = 0; i < 4; i++)
      af[i] = *(const s8v*)&As[(wm * 64 + i * 16 + p) * 72 + ko];
    #pragma unroll
    for (int j = 0; j < 4; j++)
      bf[j] = *(const s8v*)&Bs[(wn * 64 + j * 16 + p) * 72 + ko];
    #pragma unroll
    for (int i = 0; i < 4; i++)
      #pragma unroll
      for (int j = 0; j < 4; j++)
        acc[i][j] = __builtin_amdgcn_mfma_f32_16x16x32_bf16(af[i], bf[j], acc[i][j], 0, 0, 0);
  }
  #pragma unroll
  for (int i = 0; i < 4; i++)
    #pragma unroll
    for (int r = 0; r < 4; r++) {
      float m = fmaxf(fmaxf(acc[i][0][r], acc[i][1][r]), fmaxf(acc[i][2][r], acc[i][3][r]));
      #pragma unroll
      for (int o = 1; o < 16; o <<= 1) m = fmaxf(m, __shfl_xor(m, o, 64));
      if (p == 0) lred[wm * 64 + i * 16 + q * 4 + r][wn] = m;
    }
  __syncthreads();
  if (t < 128) gm[t] = fmaxf(lred[t][0], lred[t][1]);
  __syncthreads();
  #pragma unroll
  for (int i = 0; i < 4; i++)
    #pragma unroll
    for (int r = 0; r < 4; r++) {
      int row = wm * 64 + i * 16 + q * 4 + r;
      float g = gm[row];
      float s = __expf(acc[i][0][r] - g) + __expf(acc[i][1][r] - g) +
                __expf(acc[i][2][r] - g) + __expf(acc[i][3][r] - g);
      #pragma unroll
      for (int o = 1; o < 16; o <<= 1) s += __shfl_xor(s, o, 64);
      if (p == 0) lsum[row][wn] = s;
    }
  __syncthreads();
  if (t < 128) {
    float2 v = make_float2(gm[t], lsum[t][0] + lsum[t][1]);
    *(float2*)(part + (((size_t)b * 1024 + rt * 128 + t) * 8 + ct) * 2) = v;
  }
}

// ---------------------------------------------------------------- combine 8 tile-partials -> rmax, rinv
__global__ void k_scomb(const float* __restrict__ part, float* __restrict__ rmax_,
                        float* __restrict__ rinv_) {
  int i = blockIdx.x * 256 + threadIdx.x;   // 16384 rows
  const float2* pp = (const float2*)(part + (size_t)i * 16);
  float2 v[8];
  #pragma unroll
  for (int k = 0; k < 8; k++) v[k] = pp[k];
  float g = v[0].x;
  #pragma unroll
  for (int k = 1; k < 8; k++) g = fmaxf(g, v[k].x);
  float s = 0.f;
  #pragma unroll
  for (int k = 0; k < 8; k++) s += v[k].y * __expf(v[k].x - g);
  rmax_[i] = g;
  rinv_[i] = 1.0f / s;
}

// ---------------------------------------------------------------- flash xr: recompute E chunks, p in LDS, xv@p
// D[c][m] = sum_n xv[c][n]*p[n][m], p[n][m]=exp(E[m][n]-rmax[n])*rinv[n] (E symmetric)
// diffT[m][c] = Xin[c][m] - D[c][m]/(1e-9+colsum[m])
__launch_bounds__(256)
__global__ void k_xratt2(const u16* __restrict__ xv_, const u16* __restrict__ xkT_,
                         const float* __restrict__ rmax_, const float* __restrict__ rinv_,
                         const float* __restrict__ XinF, long xinF_bs,
                         u16* __restrict__ diffT) {
  __shared__ u16 pool[20736];  // Km 128x72 | Kn 32x72 | As 128x36 | Bs 128x36 ; reuse: T 128x136
  __shared__ float colred[128][2];
  u16* Km = pool;
  u16* Kn = pool + 9216;
  u16* As = pool + 11520;
  u16* Bs = pool + 16128;
  int t = threadIdx.x;
  int l = t & 63, w = t >> 6;
  int p = l & 15, q = l >> 4;
  int wm = w >> 1, wn = w & 1;
  int bid = blockIdx.x;
  int mt = bid & 7, ct = (bid >> 3) & 1, b = bid >> 4;
  int c0 = ct * 128, m0 = mt * 128;
  const u16* xvp = xv_ + (size_t)b * 262144;
  const u16* xkp = xkT_ + (size_t)b * 65536;
  const float* rmx = rmax_ + (b << 10);
  const float* riv = rinv_ + (b << 10);
  {   // persistent Km = xkT[m0..m0+128][64]
    int kg = (t & 7) * 8;
    int r0 = t >> 3;
    #pragma unroll
    for (int it = 0; it < 4; it++) {
      int r = it * 32 + r0;
      *(float4*)&Km[r * 72 + kg] = *(const float4*)(xkp + (size_t)(m0 + r) * 64 + kg);
    }
  }
  f4v acc[4][4];
  float colp[4][4];
  #pragma unroll
  for (int i = 0; i < 4; i++)
    #pragma unroll
    for (int j = 0; j < 4; j++) { acc[i][j] = (f4v){0.f, 0.f, 0.f, 0.f}; colp[i][j] = 0.f; }
  for (int k0 = 0; k0 < 1024; k0 += 32) {
    __syncthreads();
    {   // As: xv[c0+r][k0..k0+32]
      int r0 = t >> 2, kg = (t & 3) * 8;
      #pragma unroll
      for (int it = 0; it < 2; it++) {
        int r = it * 64 + r0;
        *(float4*)&As[r * 36 + kg] = *(const float4*)(xvp + (size_t)(c0 + r) * 1024 + k0 + kg);
      }
    }
    {   // Kn: xkT[k0+row][64]
      int row = t >> 3, kg = (t & 7) * 8;
      *(float4*)&Kn[row * 72 + kg] = *(const float4*)(xkp + (size_t)(k0 + row) * 64 + kg);
    }
    __syncthreads();
    // E chunk [128 m][32 n], K=64
    f4v Ef[4];
    s8v be0 = *(const s8v*)&Kn[(wn * 16 + p) * 72 + q * 8];
    s8v be1 = *(const s8v*)&Kn[(wn * 16 + p) * 72 + 32 + q * 8];
    #pragma unroll
    for (int i = 0; i < 4; i++) {
      s8v a0 = *(const s8v*)&Km[(wm * 64 + i * 16 + p) * 72 + q * 8];
      s8v a1 = *(const s8v*)&Km[(wm * 64 + i * 16 + p) * 72 + 32 + q * 8];
      Ef[i] = __builtin_amdgcn_mfma_f32_16x16x32_bf16(a0, be0, (f4v){0.f, 0.f, 0.f, 0.f}, 0, 0, 0);
      Ef[i] = __builtin_amdgcn_mfma_f32_16x16x32_bf16(a1, be1, Ef[i], 0, 0, 0);
    }
    // transform -> p bf16 in Bs[m][n]; accumulate colsums (lane's n fixed per chunk)
    int n = k0 + wn * 16 + p;
    float rm = rmx[n], ri = riv[n];
    #pragma unroll
    for (int i = 0; i < 4; i++)
      #pragma unroll
      for (int r = 0; r < 4; r++) {
        float pv = __expf(Ef[i][r] - rm) * ri;
        colp[i][r] += pv;
        Bs[(wm * 64 + i * 16 + q * 4 + r) * 36 + wn * 16 + p] = f2b(pv);
      }
    __syncthreads();
    s8v af[4], bf[4];
    #pragma unroll
    for (int i = 0; i < 4; i++)
      af[i] = *(const s8v*)&As[(wm * 64 + i * 16 + p) * 36 + q * 8];
    #pragma unroll
    for (int j = 0; j < 4; j++)
      bf[j] = *(const s8v*)&Bs[(wn * 64 + j * 16 + p) * 36 + q * 8];
    #pragma unroll
    for (int i = 0; i < 4; i++)
      #pragma unroll
      for (int j = 0; j < 4; j++)
        acc[i][j] = __builtin_amdgcn_mfma_f32_16x16x32_bf16(af[i], bf[j], acc[i][j], 0, 0, 0);
  }
  // colsum reduce: over p lanes then across wn via LDS
  #pragma unroll
  for (int i = 0; i < 4; i++)
    #pragma unroll
    for (int r = 0; r < 4; r++) {
      float s = colp[i][r];
      #pragma unroll
      for (int o = 1; o < 16; o <<= 1) s += __shfl_xor(s, o, 64);
      if (p == 0) colred[wm * 64 + i * 16 + q * 4 + r][wn] = s;
    }
  __syncthreads();
  float csv[4];
  #pragma unroll
  for (int j = 0; j < 4; j++) {
    int no = wn * 64 + j * 16 + p;
    csv[j] = 1.0f / (1e-9f + colred[no][0] + colred[no][1]);
  }
  // diff + transpose through LDS (stride 136)
  u16* T = pool;
  #pragma unroll
  for (int i = 0; i < 4; i++)
    #pragma unroll
    for (int r = 0; r < 4; r++) {
      int cl = wm * 64 + i * 16 + q * 4 + r;
      int c = c0 + cl;
      #pragma unroll
      for (int j = 0; j < 4; j++) {
        int ml = wn * 64 + j * 16 + p;
        float v = acc[i][j][r] * csv[j];
        float rv = XinF[(size_t)b * xinF_bs + (size_t)c * 1024 + m0 + ml];
        T[ml * 136 + cl] = f2b(rv - v);
      }
    }
  __syncthreads();
  int rr0 = t >> 4, cg = (t & 15) * 8;
  #pragma unroll
  for (int k = 0; k < 8; k++) {
    int rr = rr0 + k * 16;
    *(float4*)(diffT + (size_t)b * 262144 + (size_t)(m0 + rr) * 256 + c0 + cg) =
        *(const float4*)&T[rr * 136 + cg];
  }
}

// ---------------------------------------------------------------- reduce 8 pool partials
__global__ void k_pool8(const float* __restrict__ pp, float* __restrict__ pool) {
  int i = blockIdx.x * 256 + threadIdx.x;  // 16*1024
  const float4* p4 = (const float4*)(pp + (size_t)i * 8);
  float4 a = p4[0], b = p4[1];
  pool[i] = fmaxf(fmaxf(fmaxf(a.x, a.y), fmaxf(a.z, a.w)),
                  fmaxf(fmaxf(b.x, b.y), fmaxf(b.z, b.w)));
}

// ---------------------------------------------------------------- small FC layers fp32
__global__ void k_fc(const float* __restrict__ in, int Cc,
                     const float* __restrict__ W,
                     const float* __restrict__ bias,
                     const float* __restrict__ bng, const float* __restrict__ bnb,
                     int act, float* __restrict__ out, int O) {
  int i = blockIdx.x * 256 + threadIdx.x;
  if (i >= BB * O) return;
  int b = i / O, o = i % O;
  const float* xp = in + (size_t)b * Cc;
  const float* wp = W + (size_t)o * Cc;
  float s = 0.f;
  for (int c = 0; c < Cc; c += 4) {
    float4 xv = *(const float4*)(xp + c);
    float4 wv = *(const float4*)(wp + c);
    s += xv.x * wv.x + xv.y * wv.y + xv.z * wv.z + xv.w * wv.w;
  }
  if (bias) s += bias[o];
  const float BNS = 0.99999500003749966f;
  if (bng) s = s * (bng[o] * BNS) + bnb[o];
  if (act == 2) s = s > 0.f ? s : 0.2f * s;
  else if (act == 1) s = fmaxf(s, 0.f);
  out[i] = s;
}

// ---------------------------------------------------------------- host
extern "C" void kernel_launch(void* const* d_in, const int* in_sizes, int n_in,
                              void* d_out, int out_size, void* d_ws, size_t ws_size,
                              hipStream_t stream) {
  const float* x        = (const float*)d_in[0];
  const float* A        = (const float*)d_in[1];
  const float* P        = (const float*)d_in[2];
  const float* cl1_wr   = (const float*)d_in[3];
  const float* cl1_wi   = (const float*)d_in[4];
  const float* cl1_br   = (const float*)d_in[5];
  const float* cl1_bi   = (const float*)d_in[6];
  const float* cl2_wr   = (const float*)d_in[7];
  const float* cl2_wi   = (const float*)d_in[8];
  const float* cl2_br   = (const float*)d_in[9];
  const float* cl2_bi   = (const float*)d_in[10];
  const float* pt_c1_w  = (const float*)d_in[11];
  const float* pt_c2_w  = (const float*)d_in[12];
  const float* pt_bn1_g = (const float*)d_in[13];
  const float* pt_bn1_b = (const float*)d_in[14];
  const float* pt_bn2_g = (const float*)d_in[15];
  const float* pt_bn2_b = (const float*)d_in[16];
  const float* sa_qk_w  = (const float*)d_in[17];
  const float* sa_v_w   = (const float*)d_in[18];
  const float* sa_v_b   = (const float*)d_in[19];
  const float* sa_t_w   = (const float*)d_in[20];
  const float* sa_t_b   = (const float*)d_in[21];
  const float* sa_bn_g  = (const float*)d_in[22];
  const float* sa_bn_b  = (const float*)d_in[23];
  const float* fuse_w   = (const float*)d_in[24];
  const float* fuse_g   = (const float*)d_in[25];
  const float* fuse_b   = (const float*)d_in[26];
  const float* lin1_w   = (const float*)d_in[27];
  const float* bn6_g    = (const float*)d_in[28];
  const float* bn6_b    = (const float*)d_in[29];
  const float* lin2_w   = (const float*)d_in[30];
  const float* lin2_b   = (const float*)d_in[31];
  const float* bn7_g    = (const float*)d_in[32];
  const float* bn7_b    = (const float*)d_in[33];
  const float* lin3_w   = (const float*)d_in[34];
  const float* lin3_b   = (const float*)d_in[35];

  float* ws = (float*)d_ws;
  // ---- workspace layout (float offsets) ----
  const size_t oPts  = 0;                         // 49152
  const size_t oS    = 65536;                     // 16777216 f scratch (aliased per phase)
  const size_t oBigT = oS + 16777216;             // 10485760 (bf16 [16][1024][1280])
  const size_t oXf0  = oBigT + 10485760;          // 4194304
  const size_t oXf1  = oXf0 + 4194304;            // 4194304
  const size_t oH1T  = oXf1 + 4194304;            // 2097152 (h1T / diffT alias)
  const size_t oH2T  = oH1T + 2097152;            // 2097152
  const size_t oXkT  = oH2T + 2097152;            // 524288
  const size_t oXv   = oXkT + 524288;             // 2097152
  const size_t oAux  = oXv + 2097152;             // 8388608: phase1 eAT+J; phase2 rmax/rinv
  const size_t oGb   = oAux + 8388608;            // 4194304 (bf16 [16384][512])
  const size_t oW1c  = oGb + 4194304;             // 131072
  const size_t oW2c  = oW1c + 131072;             // 131072
  const size_t oCb1  = oW2c + 131072;             // 512
  const size_t oCb2  = oCb1 + 512;                // 512
  const size_t oPool = oCb2 + 512;                // 16384
  const size_t oFc1  = oPool + 16384;             // 8192
  const size_t oFc2  = oFc1 + 8192;               // 4096
  const size_t oWp   = oFc2 + 4096;               // bf16 weight pool

  float*  pts  = ws + oPts;
  // scratch S aliases: phase1 eA|Mj -> G1b|G2b -> partP|poolP
  float2* eA   = (float2*)(ws + oS);
  float2* Mj   = (float2*)(ws + oS + 8388608);
  u16*    G1b  = (u16*)(ws + oS);
  u16*    G2b  = (u16*)(ws + oS + 8388608);
  float*  partP= ws + oS;                         // [16][1024][8][2]
  float*  poolP= ws + oS + 262144;                // [16][1024][8]
  u16*    bigT = (u16*)(ws + oBigT);
  float*  Xf0  = ws + oXf0;
  float*  Xf1  = ws + oXf1;
  u16*    h1T  = (u16*)(ws + oH1T);
  u16*    diffT= (u16*)(ws + oH1T);
  u16*    h2T  = (u16*)(ws + oH2T);
  u16*    xkT  = (u16*)(ws + oXkT);
  u16*    xv   = (u16*)(ws + oXv);
  u16*    eAT  = (u16*)(ws + oAux);               // phase1
  u16*    Jb   = (u16*)(ws + oAux + 4194304);     // phase1
  float*  rmax = ws + oAux;                       // phase2 (eAT dead)
  float*  rinv = ws + oAux + 16384;
  u16*    Gb   = (u16*)(ws + oGb);
  u16*    W1c  = (u16*)(ws + oW1c);
  u16*    W2c  = (u16*)(ws + oW2c);
  float*  cb1  = ws + oCb1;
  float*  cb2  = ws + oCb2;
  float*  pool = ws + oPool;
  float*  fc1  = ws + oFc1;
  float*  fc2  = ws + oFc2;
  u16*    wp   = (u16*)(ws + oWp);
  u16* wp_pt1  = wp;
  u16* wp_pt2  = wp + 65536;
  u16* wp_qk   = wp + 131072;
  u16* wp_v    = wp + 196608;
  u16* wp_t    = wp + 458752;
  u16* wp_fuse = wp + 720896;

  // ---- weight prep ----
  k_cast<<<256, 256, 0, stream>>>(pt_c1_w, wp_pt1, 65536);
  k_cast<<<256, 256, 0, stream>>>(pt_c2_w, wp_pt2, 65536);
  k_cast<<<256, 256, 0, stream>>>(sa_qk_w, wp_qk, 65536);
  k_cast<<<1024, 256, 0, stream>>>(sa_v_w, wp_v, 262144);
  k_cast<<<1024, 256, 0, stream>>>(sa_t_w, wp_t, 262144);
  k_cast<<<5120, 256, 0, stream>>>(fuse_w, wp_fuse, 1310720);
  k_wprep<<<1024, 256, 0, stream>>>(cl1_wr, cl1_wi, W1c);
  k_wprep<<<1024, 256, 0, stream>>>(cl2_wr, cl2_wi, W2c);
  k_cbias<<<1, 512, 0, stream>>>(cl1_br, cl1_bi, cb1);
  k_cbias<<<1, 512, 0, stream>>>(cl2_br, cl2_bi, cb2);

  // ---- VecKM: M = J @ eA via MFMA ----
  k_pts<<<64, 256, 0, stream>>>(x, pts);
  k_phase<<<16384, 256, 0, stream>>>(pts, A, eA);
  k_eat<<<2048, 256, 0, stream>>>(eA, eAT);
  k_jbuild<<<16384, 256, 0, stream>>>(pts, Jb);
  k_mm<128><<<512, 256, 0, stream>>>(Jb, 1048576, 1024, eAT, 524288, 1024, 1024, 8, 4,
      nullptr, nullptr, nullptr, nullptr, 0, nullptr, 0, 0,
      (float*)Mj, 524288, 512, nullptr, 0, 0, 0, nullptr, 0, 0, nullptr);
  k_norm<<<BB * NN, 256, 0, stream>>>(Mj, eA, pts, P, Gb);

  // ---- complex linears as single real MFMA GEMMs (K=512) ----
  k_mm<128><<<512, 256, 0, stream>>>(Gb, 0, 512, W1c, 0, 512, 512, 128, 4,
      nullptr, nullptr, nullptr, cb1, 1, nullptr, 0, 0,
      nullptr, 0, 0, G1b, 0, 512, 1, nullptr, 0, 0, nullptr);
  k_mm<128><<<512, 256, 0, stream>>>(G1b, 0, 512, W2c, 0, 512, 512, 128, 4,
      nullptr, nullptr, nullptr, cb2, 0, nullptr, 0, 0,
      nullptr, 0, 0, G2b, 0, 512, 1, nullptr, 0, 0, nullptr);
  k_g2<<<16384, 256, 0, stream>>>(G2b, bigT);

  const long bsBigT = 1310720;   // ushort units
  const long bsH256 = 262144;
  const long bsXkT  = 65536;
  const long bsXvU  = 262144;
  const long bsF    = 262144;

  // ---- pt convs ----
  k_mm<128><<<256, 256, 0, stream>>>(wp_pt1, 0, 256, bigT + 1024, bsBigT, 1280, 256, 2, 8,
      nullptr, pt_bn1_g, pt_bn1_b, nullptr, 1, nullptr, 0, 0,
      nullptr, 0, 0, nullptr, 0, 0, 0, h1T, bsH256, 256, nullptr);
  k_mm<128><<<256, 256, 0, stream>>>(wp_pt2, 0, 256, h1T, bsH256, 256, 256, 2, 8,
      nullptr, pt_bn2_g, pt_bn2_b, nullptr, 1, nullptr, 0, 0,
      Xf0, bsF, 1024, nullptr, 0, 0, 0, h2T, bsH256, 256, nullptr);

  // ---- 4 SA layers (flash attention, E never materialized) ----
  for (int i = 0; i < 4; i++) {
    const u16* XinT   = (i == 0) ? h2T : (bigT + (i - 1) * 256);
    long       xinT_bs= (i == 0) ? bsH256 : bsBigT;
    int        xinT_ld= (i == 0) ? 256 : 1280;
    float*     XinF   = (i & 1) ? Xf1 : Xf0;
    float*     XoutF  = (i & 1) ? Xf0 : Xf1;
    const u16* qkw = wp_qk + (size_t)i * 16384;
    const u16* vw  = wp_v + (size_t)i * 65536;
    const u16* tw  = wp_t + (size_t)i * 65536;

    k_mm<64><<<128, 256, 0, stream>>>(qkw, 0, 256, XinT, xinT_bs, xinT_ld, 256, 1, 8,
        nullptr, nullptr, nullptr, nullptr, 0, nullptr, 0, 0,
        nullptr, 0, 0, nullptr, 0, 0, 0, xkT, bsXkT, 64, nullptr);
    k_estats<<<1024, 256, 0, stream>>>(xkT, partP);
    k_scomb<<<64, 256, 0, stream>>>(partP, rmax, rinv);
    k_mm<128><<<256, 256, 0, stream>>>(vw, 0, 256, XinT, xinT_bs, xinT_ld, 256, 2, 8,
        sa_v_b + i * 256, nullptr, nullptr, nullptr, 0, nullptr, 0, 0,
        nullptr, 0, 0, xv, bsXvU, 1024, 0, nullptr, 0, 0, nullptr);
    k_xratt2<<<256, 256, 0, stream>>>(xv, xkT, rmax, rinv, XinF, bsF, diffT);
    k_mm<128><<<256, 256, 0, stream>>>(tw, 0, 256, diffT, bsH256, 256, 256, 2, 8,
        sa_t_b + i * 256, sa_bn_g + i * 256, sa_bn_b + i * 256, nullptr, 1,
        XinF, bsF, 0,
        XoutF, bsF, 1024, nullptr, 0, 0, 0, bigT + i * 256, bsBigT, 1280, nullptr);
  }

  // ---- fuse conv with fused max pool ----
  k_mm<128><<<1024, 256, 0, stream>>>(wp_fuse, 0, 1280, bigT, bsBigT, 1280, 1280, 8, 8,
      nullptr, fuse_g, fuse_b, nullptr, 2, nullptr, 0, 0,
      nullptr, 0, 0, nullptr, 0, 0, 0, nullptr, 0, 0, poolP);
  k_pool8<<<64, 256, 0, stream>>>(poolP, pool);

  // ---- MLP head ----
  k_fc<<<32, 256, 0, stream>>>(pool, 1024, lin1_w, nullptr, bn6_g, bn6_b, 2, fc1, 512);
  k_fc<<<16, 256, 0, stream>>>(fc1, 512, lin2_w, lin2_b, bn7_g, bn7_b, 2, fc2, 256);
  k_fc<<<3, 256, 0, stream>>>(fc2, 256, lin3_w, lin3_b, nullptr, nullptr, 0, (float*)d_out, 40);
}

// Round 5
// 1105.253 us; speedup vs baseline: 1.3884x; 1.3884x over previous
//
#include <hip/hip_runtime.h>
#include <math.h>

#define BB 16
#define NN 1024
#define DD 256

typedef unsigned short u16;
typedef unsigned int uint32;
typedef __attribute__((ext_vector_type(8))) short s8v;   // 8 bf16 (4 VGPRs)
typedef __attribute__((ext_vector_type(4))) float f4v;   // 4 fp32 acc

__device__ __forceinline__ u16 f2b(float f) {            // RNE fp32->bf16
  uint32 u = __float_as_uint(f);
  return (u16)((u + 0x7fffu + ((u >> 16) & 1u)) >> 16);
}
__device__ __forceinline__ float b2f(u16 u) {
  return __uint_as_float(((uint32)u) << 16);
}
__device__ __forceinline__ float blo(uint32 w) { return __uint_as_float(w << 16); }
__device__ __forceinline__ float bhi(uint32 w) { return __uint_as_float(w & 0xffff0000u); }

__device__ __forceinline__ float waveRedSum(float v) {
  #pragma unroll
  for (int o = 32; o; o >>= 1) v += __shfl_xor(v, o, 64);
  return v;
}
__device__ __forceinline__ float waveRedMax(float v) {
  #pragma unroll
  for (int o = 32; o; o >>= 1) v = fmaxf(v, __shfl_xor(v, o, 64));
  return v;
}

// ---------------------------------------------------------------- pts [B,N,3]
__global__ void k_pts(const float* __restrict__ x, float* __restrict__ pts) {
  int i = blockIdx.x * 256 + threadIdx.x;
  if (i >= BB * NN) return;
  int b = i >> 10, n = i & 1023;
  const float* xb = x + (size_t)b * 3 * NN;
  pts[i * 3 + 0] = xb[n];
  pts[i * 3 + 1] = xb[NN + n];
  pts[i * 3 + 2] = xb[2 * NN + n];
}

// ---------------------------------------------------------------- eA fp32 [bn][256] float2
__global__ void k_phase(const float* __restrict__ pts, const float* __restrict__ A,
                        float2* __restrict__ eA) {
  int i = blockIdx.x * 256 + threadIdx.x;            // (b*N+n)*256 + d
  int d = i & 255; int bn = i >> 8;
  float p0 = pts[bn * 3], p1 = pts[bn * 3 + 1], p2 = pts[bn * 3 + 2];
  float ta = p0 * A[d] + p1 * A[256 + d] + p2 * A[512 + d];
  float s, c;
  sincosf(ta, &s, &c); eA[i] = make_float2(c, s);
}

// ---------------------------------------------------------------- eA -> eAT bf16 [b][512][1024]
__global__ void k_eat(const float2* __restrict__ eA, u16* __restrict__ eAT) {
  int bid = blockIdx.x;
  int dt = bid & 7, nt = (bid >> 3) & 15, b = bid >> 7;
  int d0 = dt * 32, n0 = nt * 64;
  __shared__ u16 cosT[32][72], sinT[32][72];
  int t = threadIdx.x;
  {
    int n = t >> 2, dg = (t & 3) * 8;
    const float2* p = eA + ((size_t)(b * 1024 + n0 + n)) * 256 + d0 + dg;
    #pragma unroll
    for (int j = 0; j < 8; j++) {
      float2 v = p[j];
      cosT[dg + j][n] = f2b(v.x);
      sinT[dg + j][n] = f2b(v.y);
    }
  }
  __syncthreads();
  {
    int rr = t >> 2, ng = (t & 3) * 16;
    int d = rr >> 1, cmp = rr & 1;
    const u16* src = (cmp ? &sinT[d][ng] : &cosT[d][ng]);
    uint4 v0 = *(const uint4*)src;
    uint4 v1 = *(const uint4*)(src + 8);
    u16* dst = eAT + ((size_t)(b * 512 + 2 * d0 + rr)) * 1024 + n0 + ng;
    *(uint4*)dst = v0;
    *(uint4*)(dst + 8) = v1;
  }
}

// ---------------------------------------------------------------- J bf16 [b][n][1024]
__global__ void k_jbuild(const float* __restrict__ pts, u16* __restrict__ J) {
  int bid = blockIdx.x;                 // b*1024 + n
  int b = bid >> 10, n = bid & 1023;
  int t = threadIdx.x;
  const float* pb = pts + (size_t)b * 3072;
  float pnx = pb[n * 3], pny = pb[n * 3 + 1], pnz = pb[n * 3 + 2];
  int m = t * 4;
  const float* pm = pb + (size_t)m * 3;
  float4 a = *(const float4*)pm;
  float4 bq = *(const float4*)(pm + 4);
  float4 c = *(const float4*)(pm + 8);
  float dx, dy, dz, d2;
  dx = a.x - pnx;  dy = a.y - pny;  dz = a.z - pnz;  d2 = dx*dx + dy*dy + dz*dz;
  float j0 = __expf(-18.0f * d2);
  dx = a.w - pnx;  dy = bq.x - pny; dz = bq.y - pnz; d2 = dx*dx + dy*dy + dz*dz;
  float j1 = __expf(-18.0f * d2);
  dx = bq.z - pnx; dy = bq.w - pny; dz = c.x - pnz;  d2 = dx*dx + dy*dy + dz*dz;
  float j2 = __expf(-18.0f * d2);
  dx = c.y - pnx;  dy = c.z - pny;  dz = c.w - pnz;  d2 = dx*dx + dy*dy + dz*dz;
  float j3 = __expf(-18.0f * d2);
  uint32 lo = (uint32)f2b(j0) | ((uint32)f2b(j1) << 16);
  uint32 hi = (uint32)f2b(j2) | ((uint32)f2b(j3) << 16);
  *(uint2*)(J + (size_t)bid * 1024 + m) = make_uint2(lo, hi);
}

// ------------------------------------------ G = norm(M*conj(eA))*16 + exp(i pts@P) -> interleaved bf16 [bn][512]
__global__ void k_norm(const float2* __restrict__ M, const float2* __restrict__ eA,
                       const float* __restrict__ pts, const float* __restrict__ P,
                       u16* __restrict__ Gb) {
  int bn = blockIdx.x; int c = threadIdx.x;
  size_t idx = (size_t)bn * DD + c;
  float2 m = M[idx], e = eA[idx];
  float gr = m.x * e.x + m.y * e.y;
  float gi = m.y * e.x - m.x * e.y;
  float s = gr * gr + gi * gi;
  s = waveRedSum(s);
  __shared__ float red[4];
  if ((c & 63) == 0) red[c >> 6] = s;
  __syncthreads();
  float tot = red[0] + red[1] + red[2] + red[3];
  float scale = 16.0f / sqrtf(tot);
  float p0 = pts[bn * 3], p1 = pts[bn * 3 + 1], p2 = pts[bn * 3 + 2];
  float tp = p0 * P[c] + p1 * P[256 + c] + p2 * P[512 + c];
  float sp, cp; sincosf(tp, &sp, &cp);
  uint32 pk = (uint32)f2b(gr * scale + cp) | ((uint32)f2b(gi * scale + sp) << 16);
  *(uint32*)(Gb + idx * 2) = pk;
}

// ---------------------------------------------------------------- weight casts / complex-weight prep
__global__ void k_cast(const float* __restrict__ s, u16* __restrict__ d, int n) {
  int i = blockIdx.x * 256 + threadIdx.x;
  if (i < n) d[i] = f2b(s[i]);
}
__global__ void k_wprep(const float* __restrict__ wr, const float* __restrict__ wi,
                        u16* __restrict__ dst) {
  int i = blockIdx.x * 256 + threadIdx.x;   // 512*512
  int op = i >> 9, c2 = i & 511, c = c2 >> 1, pl = c2 & 1;
  float v;
  if (op < 256) v = pl ? -wi[op * 256 + c] : wr[op * 256 + c];
  else          v = pl ?  wr[(op - 256) * 256 + c] : wi[(op - 256) * 256 + c];
  dst[i] = f2b(v);
}
__global__ void k_cbias(const float* __restrict__ br, const float* __restrict__ bi,
                        float* __restrict__ cb) {
  int t = threadIdx.x;
  cb[t] = (t < 256) ? br[t] : bi[t - 256];
}

// ---------------------------------------------------------------- Gr=|G|^2 -> bigT[:,1024+c] bf16
__global__ void k_g2(const u16* __restrict__ G2b, u16* __restrict__ bigT) {
  int i = blockIdx.x * 256 + threadIdx.x;   // 16384*256
  int row = i >> 8, c = i & 255;
  float re = b2f(G2b[(size_t)row * 512 + 2 * c]);
  float im = b2f(G2b[(size_t)row * 512 + 2 * c + 1]);
  bigT[(size_t)row * 1280 + 1024 + c] = f2b(re * re + im * im);
}

// ---------------------------------------------------------------- generic bf16 MFMA GEMM
// D[M][N] = A[M][K] * Bt[N][K]^T  (both bf16, k-contiguous), fp32 accum.
template<int BM>
__launch_bounds__(256)
__global__ void k_mm(const u16* __restrict__ Ab, long a_bs, int lda,
                     const u16* __restrict__ Btb, long b_bs, int ldb,
                     int K, int tiles_m, int tiles_n,
                     const float* __restrict__ bias,
                     const float* __restrict__ bng, const float* __restrict__ bnb,
                     const float* __restrict__ cbias,
                     int act,
                     const float* __restrict__ res, long res_bs, int res_sub,
                     float* __restrict__ outF, long outF_bs, int ldF,
                     u16* __restrict__ outB, long outB_bs, int ldBo, int ileave,
                     u16* __restrict__ outT, long outT_bs, int ldT,
                     float* __restrict__ outPool) {
  constexpr int BN = 128;
  constexpr int WM = (BM == 128) ? 64 : 32;
  constexpr int MI = WM / 16;
  __shared__ u16 smem[BN * BM];            // >= As(BM*32)+Bs(BN*32); also T[BN][BM] / pool red
  u16* As = smem;
  u16* Bs = smem + BM * 32;
  int t = threadIdx.x;
  int l = t & 63, w = t >> 6;
  int p = l & 15, q = l >> 4;
  int bid = blockIdx.x;
  int tn = bid % tiles_n;
  int tm = (bid / tiles_n) % tiles_m;
  int b  = bid / (tiles_n * tiles_m);
  int m0 = tm * BM, n0 = tn * BN;
  int wm = w >> 1, wn = w & 1;
  const u16* Ap = Ab + (size_t)b * a_bs;
  const u16* Bp = Btb + (size_t)b * b_bs;

  f4v acc[MI][4];
  #pragma unroll
  for (int i = 0; i < MI; i++)
    #pragma unroll
    for (int j = 0; j < 4; j++) acc[i][j] = (f4v){0.f, 0.f, 0.f, 0.f};

  int arow = t >> 2, kg = (t & 3) * 8;
  for (int k0 = 0; k0 < K; k0 += 32) {
    __syncthreads();
    #pragma unroll
    for (int it = 0; it < BM / 64; it++) {
      int r = it * 64 + arow;
      float4 v = *(const float4*)(Ap + (size_t)(m0 + r) * lda + k0 + kg);
      *(float4*)&As[r * 32 + kg] = v;
    }
    #pragma unroll
    for (int it = 0; it < 2; it++) {
      int r = it * 64 + arow;
      float4 v = *(const float4*)(Bp + (size_t)(n0 + r) * ldb + k0 + kg);
      *(float4*)&Bs[r * 32 + kg] = v;
    }
    __syncthreads();
    s8v af[MI], bf[4];
    #pragma unroll
    for (int i = 0; i < MI; i++)
      af[i] = *(const s8v*)&As[(wm * WM + i * 16 + p) * 32 + q * 8];
    #pragma unroll
    for (int j = 0; j < 4; j++)
      bf[j] = *(const s8v*)&Bs[(wn * 64 + j * 16 + p) * 32 + q * 8];
    #pragma unroll
    for (int i = 0; i < MI; i++)
      #pragma unroll
      for (int j = 0; j < 4; j++)
        acc[i][j] = __builtin_amdgcn_mfma_f32_16x16x32_bf16(af[i], bf[j], acc[i][j], 0, 0, 0);
  }

  __syncthreads();   // LDS reuse (transpose / pool reduce)

  float cbv[4];
  #pragma unroll
  for (int j = 0; j < 4; j++) {
    int no = n0 + wn * 64 + j * 16 + p;
    cbv[j] = cbias ? cbias[no] : 0.0f;
  }
  float pmax[MI][4];
  #pragma unroll
  for (int i = 0; i < MI; i++)
    #pragma unroll
    for (int r = 0; r < 4; r++) pmax[i][r] = -3.0e38f;
  const float BNS = 0.99999500003749966f;  // 1/sqrt(1+1e-5)
  #pragma unroll
  for (int i = 0; i < MI; i++) {
    #pragma unroll
    for (int r = 0; r < 4; r++) {
      int mo = m0 + wm * WM + i * 16 + q * 4 + r;
      float mult = 1.f, add = 0.f;
      if (bias) add = bias[mo];
      if (bng) { float s = bng[mo] * BNS; add = add * s + bnb[mo]; mult = s; }
      #pragma unroll
      for (int j = 0; j < 4; j++) {
        int no = n0 + wn * 64 + j * 16 + p;
        float v = acc[i][j][r];
        v = v * mult + add;
        if (cbias) v += cbv[j];
        if (act == 1) v = fmaxf(v, 0.f);
        else if (act == 2) v = v > 0.f ? v : 0.2f * v;
        if (res) {
          float rv = res[(size_t)b * res_bs + (size_t)mo * NN + no];
          v = res_sub ? rv - v : rv + v;
        }
        if (outPool) pmax[i][r] = fmaxf(pmax[i][r], v);
        if (outF) outF[(size_t)b * outF_bs + (size_t)mo * ldF + no] = v;
        if (outB) {
          int noo = ileave ? (((no & 255) << 1) | (no >> 8)) : no;
          outB[(size_t)b * outB_bs + (size_t)mo * ldBo + noo] = f2b(v);
        }
        if (outT) smem[(wn * 64 + j * 16 + p) * BM + (mo - m0)] = f2b(v);
      }
    }
  }
  if (outT) {
    __syncthreads();
    constexpr int CPR = BM / 8;            // threads per row (8 bf16 each)
    constexpr int RPP = 256 / CPR;
    int row0 = t / CPR, cg = (t % CPR) * 8;
    for (int rr = row0; rr < BN; rr += RPP) {
      float4 v = *(const float4*)&smem[rr * BM + cg];
      *(float4*)(outT + (size_t)b * outT_bs + (size_t)(n0 + rr) * ldT + m0 + cg) = v;
    }
  }
  if (outPool) {
    float* pf = (float*)smem;              // [BM][2]
    #pragma unroll
    for (int i = 0; i < MI; i++)
      #pragma unroll
      for (int r = 0; r < 4; r++) {
        float m = pmax[i][r];
        #pragma unroll
        for (int o = 1; o < 16; o <<= 1) m = fmaxf(m, __shfl_xor(m, o, 64));
        if (p == 0) pf[(wm * WM + i * 16 + q * 4 + r) * 2 + wn] = m;
      }
    __syncthreads();
    if (t < BM) {
      float mv = fmaxf(pf[t * 2], pf[t * 2 + 1]);
      outPool[((size_t)b * (tiles_m * BM) + m0 + t) * tiles_n + tn] = mv;
    }
  }
}

// ---------------------------------------------------------------- row max + 1/sum(exp) of E (bf16)
__global__ void k_rowstats(const u16* __restrict__ E, float* __restrict__ rmax_,
                           float* __restrict__ rinv_) {
  int row = blockIdx.x;                      // b*1024 + n
  const u16* pp = E + (size_t)row * NN;
  int t = threadIdx.x;
  uint2 wv = *(const uint2*)(pp + t * 4);
  float v0 = blo(wv.x), v1 = bhi(wv.x), v2 = blo(wv.y), v3 = bhi(wv.y);
  float mx = fmaxf(fmaxf(v0, v1), fmaxf(v2, v3));
  mx = waveRedMax(mx);
  __shared__ float redm[4];
  __shared__ float reds[4];
  if ((t & 63) == 0) redm[t >> 6] = mx;
  __syncthreads();
  mx = fmaxf(fmaxf(redm[0], redm[1]), fmaxf(redm[2], redm[3]));
  float s = __expf(v0 - mx) + __expf(v1 - mx) + __expf(v2 - mx) + __expf(v3 - mx);
  s = waveRedSum(s);
  if ((t & 63) == 0) reds[t >> 6] = s;
  __syncthreads();
  if (t == 0) {
    float tot = reds[0] + reds[1] + reds[2] + reds[3];
    rmax_[row] = mx;
    rinv_[row] = 1.0f / tot;
  }
}

// ---------------------------------------------------------------- fused softmax+colsum+xr+diff (E bf16, symmetric)
// D[c][m] = sum_n xv[c][n] * p[n][m],  p[n][m] = exp(E[m][n]-rmax[n])*rinv[n]
// diffT[m][c] = Xin[c][m] - D[c][m] / (1e-9 + colsum[m])
__launch_bounds__(256)
__global__ void k_xratt(const u16* __restrict__ xv_, const u16* __restrict__ E,
                        const float* __restrict__ rmax_, const float* __restrict__ rinv_,
                        const float* __restrict__ XinF, long xinF_bs,
                        u16* __restrict__ diffT) {
  __shared__ u16 smem[16384];          // As(0..4095) Bs(4096..8191); reuse: 128x128 transpose
  __shared__ float colred[128][4];
  u16* As = smem;
  u16* Bs = smem + 4096;
  int t = threadIdx.x;
  int l = t & 63, w = t >> 6;
  int p = l & 15, q = l >> 4;
  int bid = blockIdx.x;
  int mt = bid & 7, ct = (bid >> 3) & 1, b = bid >> 4;
  int c0 = ct * 128, m0 = mt * 128;
  int wm = w >> 1, wn = w & 1;
  const u16* Ap = xv_ + (size_t)b * 262144;
  const u16* Ep = E + ((size_t)b << 20);
  const float* rmx = rmax_ + (b << 10);
  const float* riv = rinv_ + (b << 10);
  f4v acc[4][4];
  #pragma unroll
  for (int i = 0; i < 4; i++)
    #pragma unroll
    for (int j = 0; j < 4; j++) acc[i][j] = (f4v){0.f, 0.f, 0.f, 0.f};
  float colpart0 = 0.f, colpart1 = 0.f;
  int arow = t >> 2, kg = (t & 3) * 8;
  for (int k0 = 0; k0 < 1024; k0 += 32) {
    __syncthreads();
    #pragma unroll
    for (int it = 0; it < 2; it++) {
      int r = it * 64 + arow;
      *(float4*)&As[r * 32 + kg] = *(const float4*)(Ap + (size_t)(c0 + r) * 1024 + k0 + kg);
    }
    float4 ma0 = *(const float4*)(rmx + k0 + kg);
    float4 ma1 = *(const float4*)(rmx + k0 + kg + 4);
    float4 ia0 = *(const float4*)(riv + k0 + kg);
    float4 ia1 = *(const float4*)(riv + k0 + kg + 4);
    #pragma unroll
    for (int it = 0; it < 2; it++) {
      int r = it * 64 + arow;
      uint4 e8 = *(const uint4*)(Ep + (size_t)(m0 + r) * 1024 + k0 + kg);
      float p0 = __expf(blo(e8.x) - ma0.x) * ia0.x;
      float p1 = __expf(bhi(e8.x) - ma0.y) * ia0.y;
      float p2 = __expf(blo(e8.y) - ma0.z) * ia0.z;
      float p3 = __expf(bhi(e8.y) - ma0.w) * ia0.w;
      float p4 = __expf(blo(e8.z) - ma1.x) * ia1.x;
      float p5 = __expf(bhi(e8.z) - ma1.y) * ia1.y;
      float p6 = __expf(blo(e8.w) - ma1.z) * ia1.z;
      float p7 = __expf(bhi(e8.w) - ma1.w) * ia1.w;
      float s8 = ((p0 + p1) + (p2 + p3)) + ((p4 + p5) + (p6 + p7));
      if (it == 0) colpart0 += s8; else colpart1 += s8;
      uint32 w0 = (uint32)f2b(p0) | ((uint32)f2b(p1) << 16);
      uint32 w1 = (uint32)f2b(p2) | ((uint32)f2b(p3) << 16);
      uint32 w2 = (uint32)f2b(p4) | ((uint32)f2b(p5) << 16);
      uint32 w3 = (uint32)f2b(p6) | ((uint32)f2b(p7) << 16);
      *(uint4*)&Bs[r * 32 + kg] = make_uint4(w0, w1, w2, w3);
    }
    __syncthreads();
    s8v af[4], bf[4];
    #pragma unroll
    for (int i = 0; i < 4; i++)
      af[i] = *(const s8v*)&As[(wm * 64 + i * 16 + p) * 32 + q * 8];
    #pragma unroll
    for (int j = 0; j < 4; j++)
      bf[j] = *(const s8v*)&Bs[(wn * 64 + j * 16 + p) * 32 + q * 8];
    #pragma unroll
    for (int i = 0; i < 4; i++)
      #pragma unroll
      for (int j = 0; j < 4; j++)
        acc[i][j] = __builtin_amdgcn_mfma_f32_16x16x32_bf16(af[i], bf[j], acc[i][j], 0, 0, 0);
  }
  colred[arow][t & 3] = colpart0;
  colred[64 + arow][t & 3] = colpart1;
  __syncthreads();
  float csv[4];
  #pragma unroll
  for (int j = 0; j < 4; j++) {
    int ml = wn * 64 + j * 16 + p;
    csv[j] = 1.0f / (1e-9f + colred[ml][0] + colred[ml][1] + colred[ml][2] + colred[ml][3]);
  }
  #pragma unroll
  for (int i = 0; i < 4; i++) {
    #pragma unroll
    for (int r = 0; r < 4; r++) {
      int cl = wm * 64 + i * 16 + q * 4 + r;
      int c = c0 + cl;
      #pragma unroll
      for (int j = 0; j < 4; j++) {
        int ml = wn * 64 + j * 16 + p;
        float v = acc[i][j][r] * csv[j];
        float rv = XinF[(size_t)b * xinF_bs + (size_t)c * 1024 + m0 + ml];
        smem[ml * 128 + cl] = f2b(rv - v);
      }
    }
  }
  __syncthreads();
  int rr0 = t >> 4, cg = (t & 15) * 8;
  #pragma unroll
  for (int k = 0; k < 8; k++) {
    int rr = rr0 + k * 16;
    *(float4*)(diffT + (size_t)b * 262144 + (size_t)(m0 + rr) * 256 + c0 + cg) =
        *(const float4*)&smem[rr * 128 + cg];
  }
}

// ---------------------------------------------------------------- reduce 8 pool partials
__global__ void k_pool8(const float* __restrict__ pp, float* __restrict__ pool) {
  int i = blockIdx.x * 256 + threadIdx.x;  // 16*1024
  const float4* p4 = (const float4*)(pp + (size_t)i * 8);
  float4 a = p4[0], b = p4[1];
  pool[i] = fmaxf(fmaxf(fmaxf(a.x, a.y), fmaxf(a.z, a.w)),
                  fmaxf(fmaxf(b.x, b.y), fmaxf(b.z, b.w)));
}

// ---------------------------------------------------------------- small FC layers fp32
__global__ void k_fc(const float* __restrict__ in, int Cc,
                     const float* __restrict__ W,
                     const float* __restrict__ bias,
                     const float* __restrict__ bng, const float* __restrict__ bnb,
                     int act, float* __restrict__ out, int O) {
  int i = blockIdx.x * 256 + threadIdx.x;
  if (i >= BB * O) return;
  int b = i / O, o = i % O;
  const float* xp = in + (size_t)b * Cc;
  const float* wp = W + (size_t)o * Cc;
  float s = 0.f;
  for (int c = 0; c < Cc; c += 4) {
    float4 xv = *(const float4*)(xp + c);
    float4 wv = *(const float4*)(wp + c);
    s += xv.x * wv.x + xv.y * wv.y + xv.z * wv.z + xv.w * wv.w;
  }
  if (bias) s += bias[o];
  const float BNS = 0.99999500003749966f;
  if (bng) s = s * (bng[o] * BNS) + bnb[o];
  if (act == 2) s = s > 0.f ? s : 0.2f * s;
  else if (act == 1) s = fmaxf(s, 0.f);
  out[i] = s;
}

// ---------------------------------------------------------------- host
extern "C" void kernel_launch(void* const* d_in, const int* in_sizes, int n_in,
                              void* d_out, int out_size, void* d_ws, size_t ws_size,
                              hipStream_t stream) {
  const float* x        = (const float*)d_in[0];
  const float* A        = (const float*)d_in[1];
  const float* P        = (const float*)d_in[2];
  const float* cl1_wr   = (const float*)d_in[3];
  const float* cl1_wi   = (const float*)d_in[4];
  const float* cl1_br   = (const float*)d_in[5];
  const float* cl1_bi   = (const float*)d_in[6];
  const float* cl2_wr   = (const float*)d_in[7];
  const float* cl2_wi   = (const float*)d_in[8];
  const float* cl2_br   = (const float*)d_in[9];
  const float* cl2_bi   = (const float*)d_in[10];
  const float* pt_c1_w  = (const float*)d_in[11];
  const float* pt_c2_w  = (const float*)d_in[12];
  const float* pt_bn1_g = (const float*)d_in[13];
  const float* pt_bn1_b = (const float*)d_in[14];
  const float* pt_bn2_g = (const float*)d_in[15];
  const float* pt_bn2_b = (const float*)d_in[16];
  const float* sa_qk_w  = (const float*)d_in[17];
  const float* sa_v_w   = (const float*)d_in[18];
  const float* sa_v_b   = (const float*)d_in[19];
  const float* sa_t_w   = (const float*)d_in[20];
  const float* sa_t_b   = (const float*)d_in[21];
  const float* sa_bn_g  = (const float*)d_in[22];
  const float* sa_bn_b  = (const float*)d_in[23];
  const float* fuse_w   = (const float*)d_in[24];
  const float* fuse_g   = (const float*)d_in[25];
  const float* fuse_b   = (const float*)d_in[26];
  const float* lin1_w   = (const float*)d_in[27];
  const float* bn6_g    = (const float*)d_in[28];
  const float* bn6_b    = (const float*)d_in[29];
  const float* lin2_w   = (const float*)d_in[30];
  const float* lin2_b   = (const float*)d_in[31];
  const float* bn7_g    = (const float*)d_in[32];
  const float* bn7_b    = (const float*)d_in[33];
  const float* lin3_w   = (const float*)d_in[34];
  const float* lin3_b   = (const float*)d_in[35];

  float* ws = (float*)d_ws;
  // ---- workspace layout (float offsets) ----
  const size_t oPts  = 0;                         // 49152
  const size_t oS    = 65536;                     // 16777216 f scratch (aliased per phase)
  const size_t oBigT = oS + 16777216;             // 10485760 (bf16 [16][1024][1280])
  const size_t oXf0  = oBigT + 10485760;          // 4194304
  const size_t oXf1  = oXf0 + 4194304;            // 4194304
  const size_t oH1T  = oXf1 + 4194304;            // 2097152 (h1T / diffT alias)
  const size_t oH2T  = oH1T + 2097152;            // 2097152
  const size_t oXkT  = oH2T + 2097152;            // 524288
  const size_t oXv   = oXkT + 524288;             // 2097152
  const size_t oAux  = oXv + 2097152;             // 8388608: phase1 eAT+J; phase2 rmax/rinv
  const size_t oGb   = oAux + 8388608;            // 4194304 (bf16 [16384][512])
  const size_t oW1c  = oGb + 4194304;             // 131072
  const size_t oW2c  = oW1c + 131072;             // 131072
  const size_t oCb1  = oW2c + 131072;             // 512
  const size_t oCb2  = oCb1 + 512;                // 512
  const size_t oPool = oCb2 + 512;                // 16384
  const size_t oFc1  = oPool + 16384;             // 8192
  const size_t oFc2  = oFc1 + 8192;               // 4096
  const size_t oWp   = oFc2 + 4096;               // bf16 weight pool

  float*  pts  = ws + oPts;
  // scratch S aliases: phase1 eA|Mj -> G1b|G2b -> Eb (bf16, 32MB) ; poolP in upper half
  float2* eA   = (float2*)(ws + oS);
  float2* Mj   = (float2*)(ws + oS + 8388608);
  u16*    G1b  = (u16*)(ws + oS);
  u16*    G2b  = (u16*)(ws + oS + 8388608);
  u16*    Eb   = (u16*)(ws + oS);                 // bf16 [16][1024][1024] = 8388608 f
  float*  poolP= ws + oS + 8388608;               // [16][1024][8]
  u16*    bigT = (u16*)(ws + oBigT);
  float*  Xf0  = ws + oXf0;
  float*  Xf1  = ws + oXf1;
  u16*    h1T  = (u16*)(ws + oH1T);
  u16*    diffT= (u16*)(ws + oH1T);
  u16*    h2T  = (u16*)(ws + oH2T);
  u16*    xkT  = (u16*)(ws + oXkT);
  u16*    xv   = (u16*)(ws + oXv);
  u16*    eAT  = (u16*)(ws + oAux);               // phase1
  u16*    Jb   = (u16*)(ws + oAux + 4194304);     // phase1
  float*  rmax = ws + oAux;                       // phase2 (eAT dead)
  float*  rinv = ws + oAux + 16384;
  u16*    Gb   = (u16*)(ws + oGb);
  u16*    W1c  = (u16*)(ws + oW1c);
  u16*    W2c  = (u16*)(ws + oW2c);
  float*  cb1  = ws + oCb1;
  float*  cb2  = ws + oCb2;
  float*  pool = ws + oPool;
  float*  fc1  = ws + oFc1;
  float*  fc2  = ws + oFc2;
  u16*    wp   = (u16*)(ws + oWp);
  u16* wp_pt1  = wp;
  u16* wp_pt2  = wp + 65536;
  u16* wp_qk   = wp + 131072;
  u16* wp_v    = wp + 196608;
  u16* wp_t    = wp + 458752;
  u16* wp_fuse = wp + 720896;

  // ---- weight prep ----
  k_cast<<<256, 256, 0, stream>>>(pt_c1_w, wp_pt1, 65536);
  k_cast<<<256, 256, 0, stream>>>(pt_c2_w, wp_pt2, 65536);
  k_cast<<<256, 256, 0, stream>>>(sa_qk_w, wp_qk, 65536);
  k_cast<<<1024, 256, 0, stream>>>(sa_v_w, wp_v, 262144);
  k_cast<<<1024, 256, 0, stream>>>(sa_t_w, wp_t, 262144);
  k_cast<<<5120, 256, 0, stream>>>(fuse_w, wp_fuse, 1310720);
  k_wprep<<<1024, 256, 0, stream>>>(cl1_wr, cl1_wi, W1c);
  k_wprep<<<1024, 256, 0, stream>>>(cl2_wr, cl2_wi, W2c);
  k_cbias<<<1, 512, 0, stream>>>(cl1_br, cl1_bi, cb1);
  k_cbias<<<1, 512, 0, stream>>>(cl2_br, cl2_bi, cb2);

  // ---- VecKM: M = J @ eA via MFMA ----
  k_pts<<<64, 256, 0, stream>>>(x, pts);
  k_phase<<<16384, 256, 0, stream>>>(pts, A, eA);
  k_eat<<<2048, 256, 0, stream>>>(eA, eAT);
  k_jbuild<<<16384, 256, 0, stream>>>(pts, Jb);
  k_mm<128><<<512, 256, 0, stream>>>(Jb, 1048576, 1024, eAT, 524288, 1024, 1024, 8, 4,
      nullptr, nullptr, nullptr, nullptr, 0, nullptr, 0, 0,
      (float*)Mj, 524288, 512, nullptr, 0, 0, 0, nullptr, 0, 0, nullptr);
  k_norm<<<BB * NN, 256, 0, stream>>>(Mj, eA, pts, P, Gb);

  // ---- complex linears as single real MFMA GEMMs (K=512) ----
  k_mm<128><<<512, 256, 0, stream>>>(Gb, 0, 512, W1c, 0, 512, 512, 128, 4,
      nullptr, nullptr, nullptr, cb1, 1, nullptr, 0, 0,
      nullptr, 0, 0, G1b, 0, 512, 1, nullptr, 0, 0, nullptr);
  k_mm<128><<<512, 256, 0, stream>>>(G1b, 0, 512, W2c, 0, 512, 512, 128, 4,
      nullptr, nullptr, nullptr, cb2, 0, nullptr, 0, 0,
      nullptr, 0, 0, G2b, 0, 512, 1, nullptr, 0, 0, nullptr);
  k_g2<<<16384, 256, 0, stream>>>(G2b, bigT);

  const long bsBigT = 1310720;   // ushort units
  const long bsH256 = 262144;
  const long bsXkT  = 65536;
  const long bsXvU  = 262144;
  const long bsF    = 262144;
  const long bsEU   = 1048576;   // Eb bf16 [1024][1024]

  // ---- pt convs ----
  k_mm<128><<<256, 256, 0, stream>>>(wp_pt1, 0, 256, bigT + 1024, bsBigT, 1280, 256, 2, 8,
      nullptr, pt_bn1_g, pt_bn1_b, nullptr, 1, nullptr, 0, 0,
      nullptr, 0, 0, nullptr, 0, 0, 0, h1T, bsH256, 256, nullptr);
  k_mm<128><<<256, 256, 0, stream>>>(wp_pt2, 0, 256, h1T, bsH256, 256, 256, 2, 8,
      nullptr, pt_bn2_g, pt_bn2_b, nullptr, 1, nullptr, 0, 0,
      Xf0, bsF, 1024, nullptr, 0, 0, 0, h2T, bsH256, 256, nullptr);

  // ---- 4 SA layers (materialized bf16 E) ----
  for (int i = 0; i < 4; i++) {
    const u16* XinT   = (i == 0) ? h2T : (bigT + (i - 1) * 256);
    long       xinT_bs= (i == 0) ? bsH256 : bsBigT;
    int        xinT_ld= (i == 0) ? 256 : 1280;
    float*     XinF   = (i & 1) ? Xf1 : Xf0;
    float*     XoutF  = (i & 1) ? Xf0 : Xf1;
    const u16* qkw = wp_qk + (size_t)i * 16384;
    const u16* vw  = wp_v + (size_t)i * 65536;
    const u16* tw  = wp_t + (size_t)i * 65536;

    // qk conv: [64][256] -> xkT bf16 [n][64]
    k_mm<64><<<128, 256, 0, stream>>>(qkw, 0, 256, XinT, xinT_bs, xinT_ld, 256, 1, 8,
        nullptr, nullptr, nullptr, nullptr, 0, nullptr, 0, 0,
        nullptr, 0, 0, nullptr, 0, 0, 0, xkT, bsXkT, 64, nullptr);
    // v conv: -> xv bf16 [c][n] (+bias)
    k_mm<128><<<256, 256, 0, stream>>>(vw, 0, 256, XinT, xinT_bs, xinT_ld, 256, 2, 8,
        sa_v_b + i * 256, nullptr, nullptr, nullptr, 0, nullptr, 0, 0,
        nullptr, 0, 0, xv, bsXvU, 1024, 0, nullptr, 0, 0, nullptr);
    // energy E = xkT * xkT^T -> bf16 [n][m] (symmetric)
    k_mm<128><<<1024, 256, 0, stream>>>(xkT, bsXkT, 64, xkT, bsXkT, 64, 64, 8, 8,
        nullptr, nullptr, nullptr, nullptr, 0, nullptr, 0, 0,
        nullptr, 0, 0, Eb, bsEU, 1024, 0, nullptr, 0, 0, nullptr);
    k_rowstats<<<BB * NN, 256, 0, stream>>>(Eb, rmax, rinv);
    k_xratt<<<256, 256, 0, stream>>>(xv, Eb, rmax, rinv, XinF, bsF, diffT);
    // t conv: relu(bn(tw@diff + tb)) + Xin -> XoutF fp32 + bigT slice bf16
    k_mm<128><<<256, 256, 0, stream>>>(tw, 0, 256, diffT, bsH256, 256, 256, 2, 8,
        sa_t_b + i * 256, sa_bn_g + i * 256, sa_bn_b + i * 256, nullptr, 1,
        XinF, bsF, 0,
        XoutF, bsF, 1024, nullptr, 0, 0, 0, bigT + i * 256, bsBigT, 1280, nullptr);
  }

  // ---- fuse conv with fused max pool ----
  k_mm<128><<<1024, 256, 0, stream>>>(wp_fuse, 0, 1280, bigT, bsBigT, 1280, 1280, 8, 8,
      nullptr, fuse_g, fuse_b, nullptr, 2, nullptr, 0, 0,
      nullptr, 0, 0, nullptr, 0, 0, 0, nullptr, 0, 0, poolP);
  k_pool8<<<64, 256, 0, stream>>>(poolP, pool);

  // ---- MLP head ----
  k_fc<<<32, 256, 0, stream>>>(pool, 1024, lin1_w, nullptr, bn6_g, bn6_b, 2, fc1, 512);
  k_fc<<<16, 256, 0, stream>>>(fc1, 512, lin2_w, lin2_b, bn7_g, bn7_b, 2, fc2, 256);
  k_fc<<<3, 256, 0, stream>>>(fc2, 256, lin3_w, lin3_b, nullptr, nullptr, 0, (float*)d_out, 40);
}

// Round 6
// 1078.861 us; speedup vs baseline: 1.4224x; 1.0245x over previous
//
#include <hip/hip_runtime.h>
#include <math.h>

#define BB 16
#define NN 1024
#define DD 256

typedef unsigned short u16;
typedef unsigned int uint32;
typedef __attribute__((ext_vector_type(8))) short s8v;   // 8 bf16 (4 VGPRs)
typedef __attribute__((ext_vector_type(4))) float f4v;   // 4 fp32 acc

__device__ __forceinline__ u16 f2b(float f) {            // RNE fp32->bf16
  uint32 u = __float_as_uint(f);
  return (u16)((u + 0x7fffu + ((u >> 16) & 1u)) >> 16);
}
__device__ __forceinline__ float b2f(u16 u) {
  return __uint_as_float(((uint32)u) << 16);
}
__device__ __forceinline__ float blo(uint32 w) { return __uint_as_float(w << 16); }
__device__ __forceinline__ float bhi(uint32 w) { return __uint_as_float(w & 0xffff0000u); }

__device__ __forceinline__ float waveRedSum(float v) {
  #pragma unroll
  for (int o = 32; o; o >>= 1) v += __shfl_xor(v, o, 64);
  return v;
}
__device__ __forceinline__ float waveRedMax(float v) {
  #pragma unroll
  for (int o = 32; o; o >>= 1) v = fmaxf(v, __shfl_xor(v, o, 64));
  return v;
}

// ---------------------------------------------------------------- pts [B,N,3]
__global__ void k_pts(const float* __restrict__ x, float* __restrict__ pts) {
  int i = blockIdx.x * 256 + threadIdx.x;
  if (i >= BB * NN) return;
  int b = i >> 10, n = i & 1023;
  const float* xb = x + (size_t)b * 3 * NN;
  pts[i * 3 + 0] = xb[n];
  pts[i * 3 + 1] = xb[NN + n];
  pts[i * 3 + 2] = xb[2 * NN + n];
}

// ---------------------------------------------------------------- eA fp32 [bn][256] float2
__global__ void k_phase(const float* __restrict__ pts, const float* __restrict__ A,
                        float2* __restrict__ eA) {
  int i = blockIdx.x * 256 + threadIdx.x;            // (b*N+n)*256 + d
  int d = i & 255; int bn = i >> 8;
  float p0 = pts[bn * 3], p1 = pts[bn * 3 + 1], p2 = pts[bn * 3 + 2];
  float ta = p0 * A[d] + p1 * A[256 + d] + p2 * A[512 + d];
  float s, c;
  sincosf(ta, &s, &c); eA[i] = make_float2(c, s);
}

// ---------------------------------------------------------------- eA -> eAT bf16 [b][512][1024]
__global__ void k_eat(const float2* __restrict__ eA, u16* __restrict__ eAT) {
  int bid = blockIdx.x;
  int dt = bid & 7, nt = (bid >> 3) & 15, b = bid >> 7;
  int d0 = dt * 32, n0 = nt * 64;
  __shared__ u16 cosT[32][72], sinT[32][72];
  int t = threadIdx.x;
  {
    int n = t >> 2, dg = (t & 3) * 8;
    const float2* p = eA + ((size_t)(b * 1024 + n0 + n)) * 256 + d0 + dg;
    #pragma unroll
    for (int j = 0; j < 8; j++) {
      float2 v = p[j];
      cosT[dg + j][n] = f2b(v.x);
      sinT[dg + j][n] = f2b(v.y);
    }
  }
  __syncthreads();
  {
    int rr = t >> 2, ng = (t & 3) * 16;
    int d = rr >> 1, cmp = rr & 1;
    const u16* src = (cmp ? &sinT[d][ng] : &cosT[d][ng]);
    uint4 v0 = *(const uint4*)src;
    uint4 v1 = *(const uint4*)(src + 8);
    u16* dst = eAT + ((size_t)(b * 512 + 2 * d0 + rr)) * 1024 + n0 + ng;
    *(uint4*)dst = v0;
    *(uint4*)(dst + 8) = v1;
  }
}

// ---------------------------------------------------------------- J bf16 [b][n][1024]
__global__ void k_jbuild(const float* __restrict__ pts, u16* __restrict__ J) {
  int bid = blockIdx.x;                 // b*1024 + n
  int b = bid >> 10, n = bid & 1023;
  int t = threadIdx.x;
  const float* pb = pts + (size_t)b * 3072;
  float pnx = pb[n * 3], pny = pb[n * 3 + 1], pnz = pb[n * 3 + 2];
  int m = t * 4;
  const float* pm = pb + (size_t)m * 3;
  float4 a = *(const float4*)pm;
  float4 bq = *(const float4*)(pm + 4);
  float4 c = *(const float4*)(pm + 8);
  float dx, dy, dz, d2;
  dx = a.x - pnx;  dy = a.y - pny;  dz = a.z - pnz;  d2 = dx*dx + dy*dy + dz*dz;
  float j0 = __expf(-18.0f * d2);
  dx = a.w - pnx;  dy = bq.x - pny; dz = bq.y - pnz; d2 = dx*dx + dy*dy + dz*dz;
  float j1 = __expf(-18.0f * d2);
  dx = bq.z - pnx; dy = bq.w - pny; dz = c.x - pnz;  d2 = dx*dx + dy*dy + dz*dz;
  float j2 = __expf(-18.0f * d2);
  dx = c.y - pnx;  dy = c.z - pny;  dz = c.w - pnz;  d2 = dx*dx + dy*dy + dz*dz;
  float j3 = __expf(-18.0f * d2);
  uint32 lo = (uint32)f2b(j0) | ((uint32)f2b(j1) << 16);
  uint32 hi = (uint32)f2b(j2) | ((uint32)f2b(j3) << 16);
  *(uint2*)(J + (size_t)bid * 1024 + m) = make_uint2(lo, hi);
}

// ------------------------------------------ G = norm(M*conj(eA))*16 + exp(i pts@P) -> interleaved bf16 [bn][512]
__global__ void k_norm(const float2* __restrict__ M, const float2* __restrict__ eA,
                       const float* __restrict__ pts, const float* __restrict__ P,
                       u16* __restrict__ Gb) {
  int bn = blockIdx.x; int c = threadIdx.x;
  size_t idx = (size_t)bn * DD + c;
  float2 m = M[idx], e = eA[idx];
  float gr = m.x * e.x + m.y * e.y;
  float gi = m.y * e.x - m.x * e.y;
  float s = gr * gr + gi * gi;
  s = waveRedSum(s);
  __shared__ float red[4];
  if ((c & 63) == 0) red[c >> 6] = s;
  __syncthreads();
  float tot = red[0] + red[1] + red[2] + red[3];
  float scale = 16.0f / sqrtf(tot);
  float p0 = pts[bn * 3], p1 = pts[bn * 3 + 1], p2 = pts[bn * 3 + 2];
  float tp = p0 * P[c] + p1 * P[256 + c] + p2 * P[512 + c];
  float sp, cp; sincosf(tp, &sp, &cp);
  uint32 pk = (uint32)f2b(gr * scale + cp) | ((uint32)f2b(gi * scale + sp) << 16);
  *(uint32*)(Gb + idx * 2) = pk;
}

// ---------------------------------------------------------------- weight casts / complex-weight prep
__global__ void k_cast(const float* __restrict__ s, u16* __restrict__ d, int n) {
  int i = blockIdx.x * 256 + threadIdx.x;
  if (i < n) d[i] = f2b(s[i]);
}
__global__ void k_wprep(const float* __restrict__ wr, const float* __restrict__ wi,
                        u16* __restrict__ dst) {
  int i = blockIdx.x * 256 + threadIdx.x;   // 512*512
  int op = i >> 9, c2 = i & 511, c = c2 >> 1, pl = c2 & 1;
  float v;
  if (op < 256) v = pl ? -wi[op * 256 + c] : wr[op * 256 + c];
  else          v = pl ?  wr[(op - 256) * 256 + c] : wi[(op - 256) * 256 + c];
  dst[i] = f2b(v);
}
__global__ void k_cbias(const float* __restrict__ br, const float* __restrict__ bi,
                        float* __restrict__ cb) {
  int t = threadIdx.x;
  cb[t] = (t < 256) ? br[t] : bi[t - 256];
}

// ---------------------------------------------------------------- Gr=|G|^2 -> bigT[:,1024+c] bf16
__global__ void k_g2(const u16* __restrict__ G2b, u16* __restrict__ bigT) {
  int i = blockIdx.x * 256 + threadIdx.x;   // 16384*256
  int row = i >> 8, c = i & 255;
  float re = b2f(G2b[(size_t)row * 512 + 2 * c]);
  float im = b2f(G2b[(size_t)row * 512 + 2 * c + 1]);
  bigT[(size_t)row * 1280 + 1024 + c] = f2b(re * re + im * im);
}

// ---------------------------------------------------------------- generic bf16 MFMA GEMM
// D[M][N] = A[M][K] * Bt[N][K]^T  (both bf16, k-contiguous), fp32 accum.
// outStats: per-M-row softmax partials over this block's 128-col tile -> [b][M][tiles_n]{max,expsum}
template<int BM>
__launch_bounds__(256)
__global__ void k_mm(const u16* __restrict__ Ab, long a_bs, int lda,
                     const u16* __restrict__ Btb, long b_bs, int ldb,
                     int K, int tiles_m, int tiles_n,
                     const float* __restrict__ bias,
                     const float* __restrict__ bng, const float* __restrict__ bnb,
                     const float* __restrict__ cbias,
                     int act,
                     const float* __restrict__ res, long res_bs, int res_sub,
                     float* __restrict__ outF, long outF_bs, int ldF,
                     u16* __restrict__ outB, long outB_bs, int ldBo, int ileave,
                     u16* __restrict__ outT, long outT_bs, int ldT,
                     float* __restrict__ outPool,
                     float* __restrict__ outStats) {
  constexpr int BN = 128;
  constexpr int WM = (BM == 128) ? 64 : 32;
  constexpr int MI = WM / 16;
  __shared__ u16 smem[BN * BM];            // >= As(BM*32)+Bs(BN*32); also T[BN][BM] / reductions
  u16* As = smem;
  u16* Bs = smem + BM * 32;
  int t = threadIdx.x;
  int l = t & 63, w = t >> 6;
  int p = l & 15, q = l >> 4;
  int bid = blockIdx.x;
  int tn = bid % tiles_n;
  int tm = (bid / tiles_n) % tiles_m;
  int b  = bid / (tiles_n * tiles_m);
  int m0 = tm * BM, n0 = tn * BN;
  int wm = w >> 1, wn = w & 1;
  const u16* Ap = Ab + (size_t)b * a_bs;
  const u16* Bp = Btb + (size_t)b * b_bs;

  f4v acc[MI][4];
  #pragma unroll
  for (int i = 0; i < MI; i++)
    #pragma unroll
    for (int j = 0; j < 4; j++) acc[i][j] = (f4v){0.f, 0.f, 0.f, 0.f};

  int arow = t >> 2, kg = (t & 3) * 8;
  for (int k0 = 0; k0 < K; k0 += 32) {
    __syncthreads();
    #pragma unroll
    for (int it = 0; it < BM / 64; it++) {
      int r = it * 64 + arow;
      float4 v = *(const float4*)(Ap + (size_t)(m0 + r) * lda + k0 + kg);
      *(float4*)&As[r * 32 + kg] = v;
    }
    #pragma unroll
    for (int it = 0; it < 2; it++) {
      int r = it * 64 + arow;
      float4 v = *(const float4*)(Bp + (size_t)(n0 + r) * ldb + k0 + kg);
      *(float4*)&Bs[r * 32 + kg] = v;
    }
    __syncthreads();
    s8v af[MI], bf[4];
    #pragma unroll
    for (int i = 0; i < MI; i++)
      af[i] = *(const s8v*)&As[(wm * WM + i * 16 + p) * 32 + q * 8];
    #pragma unroll
    for (int j = 0; j < 4; j++)
      bf[j] = *(const s8v*)&Bs[(wn * 64 + j * 16 + p) * 32 + q * 8];
    #pragma unroll
    for (int i = 0; i < MI; i++)
      #pragma unroll
      for (int j = 0; j < 4; j++)
        acc[i][j] = __builtin_amdgcn_mfma_f32_16x16x32_bf16(af[i], bf[j], acc[i][j], 0, 0, 0);
  }

  __syncthreads();   // LDS reuse (transpose / reductions)

  float cbv[4];
  #pragma unroll
  for (int j = 0; j < 4; j++) {
    int no = n0 + wn * 64 + j * 16 + p;
    cbv[j] = cbias ? cbias[no] : 0.0f;
  }
  float pmax[MI][4];
  #pragma unroll
  for (int i = 0; i < MI; i++)
    #pragma unroll
    for (int r = 0; r < 4; r++) pmax[i][r] = -3.0e38f;
  const float BNS = 0.99999500003749966f;  // 1/sqrt(1+1e-5)
  #pragma unroll
  for (int i = 0; i < MI; i++) {
    #pragma unroll
    for (int r = 0; r < 4; r++) {
      int mo = m0 + wm * WM + i * 16 + q * 4 + r;
      float mult = 1.f, add = 0.f;
      if (bias) add = bias[mo];
      if (bng) { float s = bng[mo] * BNS; add = add * s + bnb[mo]; mult = s; }
      #pragma unroll
      for (int j = 0; j < 4; j++) {
        int no = n0 + wn * 64 + j * 16 + p;
        float v = acc[i][j][r];
        v = v * mult + add;
        if (cbias) v += cbv[j];
        if (act == 1) v = fmaxf(v, 0.f);
        else if (act == 2) v = v > 0.f ? v : 0.2f * v;
        if (res) {
          float rv = res[(size_t)b * res_bs + (size_t)mo * NN + no];
          v = res_sub ? rv - v : rv + v;
        }
        if (outPool) pmax[i][r] = fmaxf(pmax[i][r], v);
        if (outF) outF[(size_t)b * outF_bs + (size_t)mo * ldF + no] = v;
        if (outB) {
          int noo = ileave ? (((no & 255) << 1) | (no >> 8)) : no;
          outB[(size_t)b * outB_bs + (size_t)mo * ldBo + noo] = f2b(v);
        }
        if (outT) smem[(wn * 64 + j * 16 + p) * BM + (mo - m0)] = f2b(v);
      }
    }
  }
  if (outT) {
    __syncthreads();
    constexpr int CPR = BM / 8;            // threads per row (8 bf16 each)
    constexpr int RPP = 256 / CPR;
    int row0 = t / CPR, cg = (t % CPR) * 8;
    for (int rr = row0; rr < BN; rr += RPP) {
      float4 v = *(const float4*)&smem[rr * BM + cg];
      *(float4*)(outT + (size_t)b * outT_bs + (size_t)(n0 + rr) * ldT + m0 + cg) = v;
    }
  }
  if (outPool) {
    float* pf = (float*)smem;              // [BM][2]
    #pragma unroll
    for (int i = 0; i < MI; i++)
      #pragma unroll
      for (int r = 0; r < 4; r++) {
        float m = pmax[i][r];
        #pragma unroll
        for (int o = 1; o < 16; o <<= 1) m = fmaxf(m, __shfl_xor(m, o, 64));
        if (p == 0) pf[(wm * WM + i * 16 + q * 4 + r) * 2 + wn] = m;
      }
    __syncthreads();
    if (t < BM) {
      float mv = fmaxf(pf[t * 2], pf[t * 2 + 1]);
      // coalesced: [b][tn][M] — each block writes BM contiguous floats
      outPool[((size_t)b * tiles_n + tn) * (size_t)(tiles_m * BM) + m0 + t] = mv;
    }
  }
  if (outStats) {
    float* sm1 = (float*)smem;             // [BM][2] max
    float* sm2 = sm1 + BM * 2;             // [BM][2] expsum
    #pragma unroll
    for (int i = 0; i < MI; i++)
      #pragma unroll
      for (int r = 0; r < 4; r++) {
        float m = fmaxf(fmaxf(acc[i][0][r], acc[i][1][r]), fmaxf(acc[i][2][r], acc[i][3][r]));
        #pragma unroll
        for (int o = 1; o < 16; o <<= 1) m = fmaxf(m, __shfl_xor(m, o, 64));
        if (p == 0) sm1[(wm * WM + i * 16 + q * 4 + r) * 2 + wn] = m;
      }
    __syncthreads();
    #pragma unroll
    for (int i = 0; i < MI; i++)
      #pragma unroll
      for (int r = 0; r < 4; r++) {
        int row = wm * WM + i * 16 + q * 4 + r;
        float g = fmaxf(sm1[row * 2], sm1[row * 2 + 1]);
        float s = __expf(acc[i][0][r] - g) + __expf(acc[i][1][r] - g) +
                  __expf(acc[i][2][r] - g) + __expf(acc[i][3][r] - g);
        #pragma unroll
        for (int o = 1; o < 16; o <<= 1) s += __shfl_xor(s, o, 64);
        if (p == 0) sm2[row * 2 + wn] = s;
      }
    __syncthreads();
    if (t < BM) {
      float g = fmaxf(sm1[t * 2], sm1[t * 2 + 1]);
      float ssum = sm2[t * 2] + sm2[t * 2 + 1];
      *(float2*)(outStats + (((size_t)b * (tiles_m * BM) + m0 + t) * tiles_n + tn) * 2)
          = make_float2(g, ssum);
    }
  }
}

// ---------------------------------------------------------------- fused softmax+colsum+xr+diff (E bf16, symmetric)
// D[c][m] = sum_n xv[c][n] * p[n][m],  p[n][m] = exp(E[m][n]-rmax[n])*rinv[n]
// rmax/rinv combined from per-tile partials in prologue (LDS).
// diffT[m][c] = Xin[c][m] - D[c][m] / (1e-9 + colsum[m])
__launch_bounds__(256)
__global__ void k_xratt(const u16* __restrict__ xv_, const u16* __restrict__ E,
                        const float* __restrict__ part_,
                        const float* __restrict__ XinF, long xinF_bs,
                        u16* __restrict__ diffT) {
  __shared__ u16 smem[16384];          // As(0..4095) Bs(4096..8191); reuse: 128x128 transpose
  __shared__ float colred[128][4];
  __shared__ float rmS[1024];
  __shared__ float riS[1024];
  u16* As = smem;
  u16* Bs = smem + 4096;
  int t = threadIdx.x;
  int l = t & 63, w = t >> 6;
  int p = l & 15, q = l >> 4;
  int bid = blockIdx.x;
  int mt = bid & 7, ct = (bid >> 3) & 1, b = bid >> 4;
  int c0 = ct * 128, m0 = mt * 128;
  int wm = w >> 1, wn = w & 1;
  const u16* Ap = xv_ + (size_t)b * 262144;
  const u16* Ep = E + ((size_t)b << 20);
  // prologue: combine 8 tile-partials per row -> rmax, 1/expsum
  {
    const float2* pbase = (const float2*)(part_ + (size_t)b * 16384);
    for (int row = t; row < 1024; row += 256) {
      const float2* pp = pbase + row * 8;
      float2 vv[8];
      #pragma unroll
      for (int k = 0; k < 8; k++) vv[k] = pp[k];
      float g = vv[0].x;
      #pragma unroll
      for (int k = 1; k < 8; k++) g = fmaxf(g, vv[k].x);
      float s = 0.f;
      #pragma unroll
      for (int k = 0; k < 8; k++) s += vv[k].y * __expf(vv[k].x - g);
      rmS[row] = g;
      riS[row] = 1.0f / s;
    }
  }
  f4v acc[4][4];
  #pragma unroll
  for (int i = 0; i < 4; i++)
    #pragma unroll
    for (int j = 0; j < 4; j++) acc[i][j] = (f4v){0.f, 0.f, 0.f, 0.f};
  float colpart0 = 0.f, colpart1 = 0.f;
  int arow = t >> 2, kg = (t & 3) * 8;
  for (int k0 = 0; k0 < 1024; k0 += 32) {
    __syncthreads();
    #pragma unroll
    for (int it = 0; it < 2; it++) {
      int r = it * 64 + arow;
      *(float4*)&As[r * 32 + kg] = *(const float4*)(Ap + (size_t)(c0 + r) * 1024 + k0 + kg);
    }
    float4 ma0 = *(const float4*)&rmS[k0 + kg];
    float4 ma1 = *(const float4*)&rmS[k0 + kg + 4];
    float4 ia0 = *(const float4*)&riS[k0 + kg];
    float4 ia1 = *(const float4*)&riS[k0 + kg + 4];
    #pragma unroll
    for (int it = 0; it < 2; it++) {
      int r = it * 64 + arow;
      uint4 e8 = *(const uint4*)(Ep + (size_t)(m0 + r) * 1024 + k0 + kg);
      float p0 = __expf(blo(e8.x) - ma0.x) * ia0.x;
      float p1 = __expf(bhi(e8.x) - ma0.y) * ia0.y;
      float p2 = __expf(blo(e8.y) - ma0.z) * ia0.z;
      float p3 = __expf(bhi(e8.y) - ma0.w) * ia0.w;
      float p4 = __expf(blo(e8.z) - ma1.x) * ia1.x;
      float p5 = __expf(bhi(e8.z) - ma1.y) * ia1.y;
      float p6 = __expf(blo(e8.w) - ma1.z) * ia1.z;
      float p7 = __expf(bhi(e8.w) - ma1.w) * ia1.w;
      float s8 = ((p0 + p1) + (p2 + p3)) + ((p4 + p5) + (p6 + p7));
      if (it == 0) colpart0 += s8; else colpart1 += s8;
      uint32 w0 = (uint32)f2b(p0) | ((uint32)f2b(p1) << 16);
      uint32 w1 = (uint32)f2b(p2) | ((uint32)f2b(p3) << 16);
      uint32 w2 = (uint32)f2b(p4) | ((uint32)f2b(p5) << 16);
      uint32 w3 = (uint32)f2b(p6) | ((uint32)f2b(p7) << 16);
      *(uint4*)&Bs[r * 32 + kg] = make_uint4(w0, w1, w2, w3);
    }
    __syncthreads();
    s8v af[4], bf[4];
    #pragma unroll
    for (int i = 0; i < 4; i++)
      af[i] = *(const s8v*)&As[(wm * 64 + i * 16 + p) * 32 + q * 8];
    #pragma unroll
    for (int j = 0; j < 4; j++)
      bf[j] = *(const s8v*)&Bs[(wn * 64 + j * 16 + p) * 32 + q * 8];
    #pragma unroll
    for (int i = 0; i < 4; i++)
      #pragma unroll
      for (int j = 0; j < 4; j++)
        acc[i][j] = __builtin_amdgcn_mfma_f32_16x16x32_bf16(af[i], bf[j], acc[i][j], 0, 0, 0);
  }
  colred[arow][t & 3] = colpart0;
  colred[64 + arow][t & 3] = colpart1;
  __syncthreads();
  float csv[4];
  #pragma unroll
  for (int j = 0; j < 4; j++) {
    int ml = wn * 64 + j * 16 + p;
    csv[j] = 1.0f / (1e-9f + colred[ml][0] + colred[ml][1] + colred[ml][2] + colred[ml][3]);
  }
  #pragma unroll
  for (int i = 0; i < 4; i++) {
    #pragma unroll
    for (int r = 0; r < 4; r++) {
      int cl = wm * 64 + i * 16 + q * 4 + r;
      int c = c0 + cl;
      #pragma unroll
      for (int j = 0; j < 4; j++) {
        int ml = wn * 64 + j * 16 + p;
        float v = acc[i][j][r] * csv[j];
        float rv = XinF[(size_t)b * xinF_bs + (size_t)c * 1024 + m0 + ml];
        smem[ml * 128 + cl] = f2b(rv - v);
      }
    }
  }
  __syncthreads();
  int rr0 = t >> 4, cg = (t & 15) * 8;
  #pragma unroll
  for (int k = 0; k < 8; k++) {
    int rr = rr0 + k * 16;
    *(float4*)(diffT + (size_t)b * 262144 + (size_t)(m0 + rr) * 256 + c0 + cg) =
        *(const float4*)&smem[rr * 128 + cg];
  }
}

// ---------------------------------------------------------------- reduce 8 pool partials ([b][tn][o] layout)
__global__ void k_pool8(const float* __restrict__ pp, float* __restrict__ pool) {
  int i = blockIdx.x * 256 + threadIdx.x;  // b*1024 + o
  int b = i >> 10, o = i & 1023;
  const float* base = pp + (size_t)b * 8192 + o;
  float m = base[0];
  #pragma unroll
  for (int tn = 1; tn < 8; tn++) m = fmaxf(m, base[tn * 1024]);
  pool[i] = m;
}

// ---------------------------------------------------------------- small FC layers fp32
__global__ void k_fc(const float* __restrict__ in, int Cc,
                     const float* __restrict__ W,
                     const float* __restrict__ bias,
                     const float* __restrict__ bng, const float* __restrict__ bnb,
                     int act, float* __restrict__ out, int O) {
  int i = blockIdx.x * 256 + threadIdx.x;
  if (i >= BB * O) return;
  int b = i / O, o = i % O;
  const float* xp = in + (size_t)b * Cc;
  const float* wp = W + (size_t)o * Cc;
  float s = 0.f;
  for (int c = 0; c < Cc; c += 4) {
    float4 xv = *(const float4*)(xp + c);
    float4 wv = *(const float4*)(wp + c);
    s += xv.x * wv.x + xv.y * wv.y + xv.z * wv.z + xv.w * wv.w;
  }
  if (bias) s += bias[o];
  const float BNS = 0.99999500003749966f;
  if (bng) s = s * (bng[o] * BNS) + bnb[o];
  if (act == 2) s = s > 0.f ? s : 0.2f * s;
  else if (act == 1) s = fmaxf(s, 0.f);
  out[i] = s;
}

// ---------------------------------------------------------------- host
extern "C" void kernel_launch(void* const* d_in, const int* in_sizes, int n_in,
                              void* d_out, int out_size, void* d_ws, size_t ws_size,
                              hipStream_t stream) {
  const float* x        = (const float*)d_in[0];
  const float* A        = (const float*)d_in[1];
  const float* P        = (const float*)d_in[2];
  const float* cl1_wr   = (const float*)d_in[3];
  const float* cl1_wi   = (const float*)d_in[4];
  const float* cl1_br   = (const float*)d_in[5];
  const float* cl1_bi   = (const float*)d_in[6];
  const float* cl2_wr   = (const float*)d_in[7];
  const float* cl2_wi   = (const float*)d_in[8];
  const float* cl2_br   = (const float*)d_in[9];
  const float* cl2_bi   = (const float*)d_in[10];
  const float* pt_c1_w  = (const float*)d_in[11];
  const float* pt_c2_w  = (const float*)d_in[12];
  const float* pt_bn1_g = (const float*)d_in[13];
  const float* pt_bn1_b = (const float*)d_in[14];
  const float* pt_bn2_g = (const float*)d_in[15];
  const float* pt_bn2_b = (const float*)d_in[16];
  const float* sa_qk_w  = (const float*)d_in[17];
  const float* sa_v_w   = (const float*)d_in[18];
  const float* sa_v_b   = (const float*)d_in[19];
  const float* sa_t_w   = (const float*)d_in[20];
  const float* sa_t_b   = (const float*)d_in[21];
  const float* sa_bn_g  = (const float*)d_in[22];
  const float* sa_bn_b  = (const float*)d_in[23];
  const float* fuse_w   = (const float*)d_in[24];
  const float* fuse_g   = (const float*)d_in[25];
  const float* fuse_b   = (const float*)d_in[26];
  const float* lin1_w   = (const float*)d_in[27];
  const float* bn6_g    = (const float*)d_in[28];
  const float* bn6_b    = (const float*)d_in[29];
  const float* lin2_w   = (const float*)d_in[30];
  const float* lin2_b   = (const float*)d_in[31];
  const float* bn7_g    = (const float*)d_in[32];
  const float* bn7_b    = (const float*)d_in[33];
  const float* lin3_w   = (const float*)d_in[34];
  const float* lin3_b   = (const float*)d_in[35];

  float* ws = (float*)d_ws;
  // ---- workspace layout (float offsets) ----
  const size_t oPts  = 0;                         // 49152
  const size_t oS    = 65536;                     // 16777216 f scratch (aliased per phase)
  const size_t oBigT = oS + 16777216;             // 10485760 (bf16 [16][1024][1280])
  const size_t oXf0  = oBigT + 10485760;          // 4194304
  const size_t oXf1  = oXf0 + 4194304;            // 4194304
  const size_t oH1T  = oXf1 + 4194304;            // 2097152 (h1T / diffT alias)
  const size_t oH2T  = oH1T + 2097152;            // 2097152
  const size_t oXkT  = oH2T + 2097152;            // 524288
  const size_t oXv   = oXkT + 524288;             // 2097152
  const size_t oAux  = oXv + 2097152;             // 8388608: phase1 eAT+J; phase2 part
  const size_t oGb   = oAux + 8388608;            // 4194304 (bf16 [16384][512])
  const size_t oW1c  = oGb + 4194304;             // 131072
  const size_t oW2c  = oW1c + 131072;             // 131072
  const size_t oCb1  = oW2c + 131072;             // 512
  const size_t oCb2  = oCb1 + 512;                // 512
  const size_t oPool = oCb2 + 512;                // 16384
  const size_t oFc1  = oPool + 16384;             // 8192
  const size_t oFc2  = oFc1 + 8192;               // 4096
  const size_t oWp   = oFc2 + 4096;               // bf16 weight pool

  float*  pts  = ws + oPts;
  // scratch S aliases: phase1 eA|Mj -> G1b|G2b -> Eb (bf16, 32MB); poolP in upper half
  float2* eA   = (float2*)(ws + oS);
  float2* Mj   = (float2*)(ws + oS + 8388608);
  u16*    G1b  = (u16*)(ws + oS);
  u16*    G2b  = (u16*)(ws + oS + 8388608);
  u16*    Eb   = (u16*)(ws + oS);                 // bf16 [16][1024][1024] = 8388608 f
  float*  poolP= ws + oS + 8388608;               // [16][8][1024]
  u16*    bigT = (u16*)(ws + oBigT);
  float*  Xf0  = ws + oXf0;
  float*  Xf1  = ws + oXf1;
  u16*    h1T  = (u16*)(ws + oH1T);
  u16*    diffT= (u16*)(ws + oH1T);
  u16*    h2T  = (u16*)(ws + oH2T);
  u16*    xkT  = (u16*)(ws + oXkT);
  u16*    xv   = (u16*)(ws + oXv);
  u16*    eAT  = (u16*)(ws + oAux);               // phase1
  u16*    Jb   = (u16*)(ws + oAux + 4194304);     // phase1
  float*  partP= ws + oAux;                       // phase2 (eAT dead): [16][1024][8][2]
  u16*    Gb   = (u16*)(ws + oGb);
  u16*    W1c  = (u16*)(ws + oW1c);
  u16*    W2c  = (u16*)(ws + oW2c);
  float*  cb1  = ws + oCb1;
  float*  cb2  = ws + oCb2;
  float*  pool = ws + oPool;
  float*  fc1  = ws + oFc1;
  float*  fc2  = ws + oFc2;
  u16*    wp   = (u16*)(ws + oWp);
  u16* wp_pt1  = wp;
  u16* wp_pt2  = wp + 65536;
  u16* wp_qk   = wp + 131072;
  u16* wp_v    = wp + 196608;
  u16* wp_t    = wp + 458752;
  u16* wp_fuse = wp + 720896;

  // ---- weight prep ----
  k_cast<<<256, 256, 0, stream>>>(pt_c1_w, wp_pt1, 65536);
  k_cast<<<256, 256, 0, stream>>>(pt_c2_w, wp_pt2, 65536);
  k_cast<<<256, 256, 0, stream>>>(sa_qk_w, wp_qk, 65536);
  k_cast<<<1024, 256, 0, stream>>>(sa_v_w, wp_v, 262144);
  k_cast<<<1024, 256, 0, stream>>>(sa_t_w, wp_t, 262144);
  k_cast<<<5120, 256, 0, stream>>>(fuse_w, wp_fuse, 1310720);
  k_wprep<<<1024, 256, 0, stream>>>(cl1_wr, cl1_wi, W1c);
  k_wprep<<<1024, 256, 0, stream>>>(cl2_wr, cl2_wi, W2c);
  k_cbias<<<1, 512, 0, stream>>>(cl1_br, cl1_bi, cb1);
  k_cbias<<<1, 512, 0, stream>>>(cl2_br, cl2_bi, cb2);

  // ---- VecKM: M = J @ eA via MFMA ----
  k_pts<<<64, 256, 0, stream>>>(x, pts);
  k_phase<<<16384, 256, 0, stream>>>(pts, A, eA);
  k_eat<<<2048, 256, 0, stream>>>(eA, eAT);
  k_jbuild<<<16384, 256, 0, stream>>>(pts, Jb);
  k_mm<128><<<512, 256, 0, stream>>>(Jb, 1048576, 1024, eAT, 524288, 1024, 1024, 8, 4,
      nullptr, nullptr, nullptr, nullptr, 0, nullptr, 0, 0,
      (float*)Mj, 524288, 512, nullptr, 0, 0, 0, nullptr, 0, 0, nullptr, nullptr);
  k_norm<<<BB * NN, 256, 0, stream>>>(Mj, eA, pts, P, Gb);

  // ---- complex linears as single real MFMA GEMMs (K=512) ----
  k_mm<128><<<512, 256, 0, stream>>>(Gb, 0, 512, W1c, 0, 512, 512, 128, 4,
      nullptr, nullptr, nullptr, cb1, 1, nullptr, 0, 0,
      nullptr, 0, 0, G1b, 0, 512, 1, nullptr, 0, 0, nullptr, nullptr);
  k_mm<128><<<512, 256, 0, stream>>>(G1b, 0, 512, W2c, 0, 512, 512, 128, 4,
      nullptr, nullptr, nullptr, cb2, 0, nullptr, 0, 0,
      nullptr, 0, 0, G2b, 0, 512, 1, nullptr, 0, 0, nullptr, nullptr);
  k_g2<<<16384, 256, 0, stream>>>(G2b, bigT);

  const long bsBigT = 1310720;   // ushort units
  const long bsH256 = 262144;
  const long bsXkT  = 65536;
  const long bsXvU  = 262144;
  const long bsF    = 262144;
  const long bsEU   = 1048576;   // Eb bf16 [1024][1024]

  // ---- pt convs ----
  k_mm<128><<<256, 256, 0, stream>>>(wp_pt1, 0, 256, bigT + 1024, bsBigT, 1280, 256, 2, 8,
      nullptr, pt_bn1_g, pt_bn1_b, nullptr, 1, nullptr, 0, 0,
      nullptr, 0, 0, nullptr, 0, 0, 0, h1T, bsH256, 256, nullptr, nullptr);
  k_mm<128><<<256, 256, 0, stream>>>(wp_pt2, 0, 256, h1T, bsH256, 256, 256, 2, 8,
      nullptr, pt_bn2_g, pt_bn2_b, nullptr, 1, nullptr, 0, 0,
      Xf0, bsF, 1024, nullptr, 0, 0, 0, h2T, bsH256, 256, nullptr, nullptr);

  // ---- 4 SA layers (materialized bf16 E, stats fused into energy GEMM) ----
  for (int i = 0; i < 4; i++) {
    const u16* XinT   = (i == 0) ? h2T : (bigT + (i - 1) * 256);
    long       xinT_bs= (i == 0) ? bsH256 : bsBigT;
    int        xinT_ld= (i == 0) ? 256 : 1280;
    float*     XinF   = (i & 1) ? Xf1 : Xf0;
    float*     XoutF  = (i & 1) ? Xf0 : Xf1;
    const u16* qkw = wp_qk + (size_t)i * 16384;
    const u16* vw  = wp_v + (size_t)i * 65536;
    const u16* tw  = wp_t + (size_t)i * 65536;

    // qk conv: [64][256] -> xkT bf16 [n][64]
    k_mm<64><<<128, 256, 0, stream>>>(qkw, 0, 256, XinT, xinT_bs, xinT_ld, 256, 1, 8,
        nullptr, nullptr, nullptr, nullptr, 0, nullptr, 0, 0,
        nullptr, 0, 0, nullptr, 0, 0, 0, xkT, bsXkT, 64, nullptr, nullptr);
    // v conv: -> xv bf16 [c][n] (+bias)
    k_mm<128><<<256, 256, 0, stream>>>(vw, 0, 256, XinT, xinT_bs, xinT_ld, 256, 2, 8,
        sa_v_b + i * 256, nullptr, nullptr, nullptr, 0, nullptr, 0, 0,
        nullptr, 0, 0, xv, bsXvU, 1024, 0, nullptr, 0, 0, nullptr, nullptr);
    // energy E = xkT * xkT^T -> bf16 [n][m] + fused per-tile softmax stats
    k_mm<128><<<1024, 256, 0, stream>>>(xkT, bsXkT, 64, xkT, bsXkT, 64, 64, 8, 8,
        nullptr, nullptr, nullptr, nullptr, 0, nullptr, 0, 0,
        nullptr, 0, 0, Eb, bsEU, 1024, 0, nullptr, 0, 0, nullptr, partP);
    k_xratt<<<256, 256, 0, stream>>>(xv, Eb, partP, XinF, bsF, diffT);
    // t conv: relu(bn(tw@diff + tb)) + Xin -> XoutF fp32 + bigT slice bf16
    k_mm<128><<<256, 256, 0, stream>>>(tw, 0, 256, diffT, bsH256, 256, 256, 2, 8,
        sa_t_b + i * 256, sa_bn_g + i * 256, sa_bn_b + i * 256, nullptr, 1,
        XinF, bsF, 0,
        XoutF, bsF, 1024, nullptr, 0, 0, 0, bigT + i * 256, bsBigT, 1280, nullptr, nullptr);
  }

  // ---- fuse conv with fused max pool (coalesced partials) ----
  k_mm<128><<<1024, 256, 0, stream>>>(wp_fuse, 0, 1280, bigT, bsBigT, 1280, 1280, 8, 8,
      nullptr, fuse_g, fuse_b, nullptr, 2, nullptr, 0, 0,
      nullptr, 0, 0, nullptr, 0, 0, 0, nullptr, 0, 0, poolP, nullptr);
  k_pool8<<<64, 256, 0, stream>>>(poolP, pool);

  // ---- MLP head ----
  k_fc<<<32, 256, 0, stream>>>(pool, 1024, lin1_w, nullptr, bn6_g, bn6_b, 2, fc1, 512);
  k_fc<<<16, 256, 0, stream>>>(fc1, 512, lin2_w, lin2_b, bn7_g, bn7_b, 2, fc2, 256);
  k_fc<<<3, 256, 0, stream>>>(fc2, 256, lin3_w, lin3_b, nullptr, nullptr, 0, (float*)d_out, 40);
}